// Round 8
// baseline (269.823 us; speedup 1.0000x reference)
//
#include <hip/hip_runtime.h>
#include <hip/hip_bf16.h>

// Problem constants
#define B_DIM 4096
#define H_DIM 1024
#define K1    2048   // IN + H
#define N1    6144   // 5 gates * 1024 + a1 (1024)
#define N2    2048   // ssg (1024) + r1 (1024)
#define NT1   (K1 / 64)   // 32 K-tiles for the big GEMM

typedef __attribute__((ext_vector_type(8))) short bf16x8;
typedef __attribute__((ext_vector_type(4))) float f32x4;

__device__ __forceinline__ unsigned short f2bf(float f) {
  unsigned int x = __float_as_uint(f);
  x += 0x7fffu + ((x >> 16) & 1u);   // RTNE
  return (unsigned short)(x >> 16);
}
__device__ __forceinline__ float bf2f(unsigned short u) {
  return __uint_as_float(((unsigned int)u) << 16);
}
__device__ __forceinline__ float fast_sigmoid(float x) {
  return __builtin_amdgcn_rcpf(1.0f + __expf(-x));
}
__device__ __forceinline__ float fast_tanh(float x) {
  return 1.0f - 2.0f * __builtin_amdgcn_rcpf(1.0f + __expf(2.0f * x));
}
__device__ __forceinline__ void gload_lds16(const void* g, void* l) {
  __builtin_amdgcn_global_load_lds(
      (const __attribute__((address_space(1))) void*)g,
      (__attribute__((address_space(3))) void*)l, 16, 0, 0);
}

// m201's st_16x32 swizzle: XOR byte-bit5 with bit9 within a 1024B subtile.
__device__ __forceinline__ int swz1k(int x) {
  return x ^ (((x >> 9) & 1) << 5);
}

// ---------------------------------------------------------------------------
// prep: build bf16 activations + weight panels in workspace (grid-stride vec4)
// ---------------------------------------------------------------------------
__global__ __launch_bounds__(256) void prep_kernel(
    const float* __restrict__ x, const float* __restrict__ h,
    const float* __restrict__ ssg_state,
    const float* __restrict__ Wx, const float* __restrict__ Ux,
    const float* __restrict__ a1_w,
    const float* __restrict__ ssg_w, const float* __restrict__ r1_w,
    const float* __restrict__ r2_w, const float* __restrict__ r3_w,
    unsigned short* __restrict__ combined,
    unsigned short* __restrict__ ssg_in,
    unsigned short* __restrict__ hprev_bf,
    unsigned short* __restrict__ W1,
    unsigned short* __restrict__ W2,
    unsigned short* __restrict__ W3,
    unsigned short* __restrict__ W4)
{
  const size_t NV0 = (size_t)B_DIM * K1 / 4;      // combined
  const size_t NV1 = (size_t)B_DIM * H_DIM / 4;   // ssg_in
  const size_t NV2 = NV1;                         // hprev
  const size_t NV3 = (size_t)N1 * K1 / 4;         // W1
  const size_t NV4 = (size_t)N2 * H_DIM / 4;      // W2
  const size_t NV5 = (size_t)H_DIM * H_DIM / 4;   // W3, W4
  const size_t total = NV0 + NV1 + NV2 + NV3 + NV4 + NV5 + NV5;
  const size_t stride = (size_t)gridDim.x * blockDim.x;

  for (size_t v = (size_t)blockIdx.x * blockDim.x + threadIdx.x; v < total; v += stride) {
    size_t idx = v;
    const float* src;
    unsigned short* dst;
    if (idx < NV0) {
      size_t e = idx * 4, b = e >> 11, k = e & 2047;
      src = (k < 1024) ? &x[(b << 10) + k] : &h[(b << 10) + (k - 1024)];
      dst = &combined[e];
    } else if ((idx -= NV0) < NV1) {
      size_t e = idx * 4;
      float4 a = *(const float4*)&ssg_state[e];
      float4 c = *(const float4*)&h[e];
      ushort4 o;
      o.x = f2bf(a.x + c.x); o.y = f2bf(a.y + c.y);
      o.z = f2bf(a.z + c.z); o.w = f2bf(a.w + c.w);
      *(ushort4*)&ssg_in[e] = o;
      continue;
    } else if ((idx -= NV1) < NV2) {
      size_t e = idx * 4; src = &h[e]; dst = &hprev_bf[e];
    } else if ((idx -= NV2) < NV3) {
      size_t e = idx * 4, n = e >> 11, k = e & 2047;
      if (n < 5120) src = (k < 1024) ? &Wx[(n << 10) + k] : &Ux[(n << 10) + (k - 1024)];
      else          src = &a1_w[((n - 5120) << 11) + k];
      dst = &W1[e];
    } else if ((idx -= NV3) < NV4) {
      size_t e = idx * 4, n = e >> 10, k = e & 1023;
      src = (n < 1024) ? &ssg_w[(n << 10) + k] : &r1_w[((n - 1024) << 10) + k];
      dst = &W2[e];
    } else if ((idx -= NV4) < NV5) {
      size_t e = idx * 4; src = &r2_w[e]; dst = &W3[e];
    } else {
      idx -= NV5;
      size_t e = idx * 4; src = &r3_w[e]; dst = &W4[e];
    }
    float4 a = *(const float4*)src;
    ushort4 o;
    o.x = f2bf(a.x); o.y = f2bf(a.y); o.z = f2bf(a.z); o.w = f2bf(a.w);
    *(ushort4*)dst = o;
  }
}

// ---------------------------------------------------------------------------
// 128x256 GEMM, ONE-barrier-per-K-tile schedule (this round's change):
// ALL staging one tile ahead: during tile t, stage A(t+1)+B(t+1) into the
// opposite buffer (holds t-1, dead: every t-1 ds_read was consumed by a t-1
// MFMA -> lgkm drained via register deps before any wave crossed the barrier).
// Per K-tile t:
//   top: vmcnt(0) [drains A(t),B(t), issued >= half a tile ago -> cheap]
//        + s_barrier
//   reads b0,a0; STAGE_A(t+1); reads b1,a1; STAGE_B(t+1) x2
//   MFMA(a0,b0); MFMA(a1,b1)          [no mid barrier, no explicit lgkm]
// Race audit: DMA(t+1) -> buf(t+1)=buf(t-1): all t-1 reads complete (reg
// deps) before the shared top barrier. Reads of buf(t) vs DMA into buf(t)
// (issued during t-1): ordered by top vmcnt(0)+barrier. Epilogue slab use
// guarded by its own barrier.
// Grid = 32x24 = 768 blocks = 3 full rounds. 16x16x32 MFMA, conflict-free
// swizzled reads (R5-verified). LDS 96KB: 2 x [A 128x64 | B 256x64].
// ---------------------------------------------------------------------------
__global__ __launch_bounds__(512, 2) void gemm8p_mode0(
    const unsigned short* __restrict__ A,
    const unsigned short* __restrict__ W,
    const float* __restrict__ bWx, const float* __restrict__ bUx,
    const float* __restrict__ a1_b,
    unsigned short* __restrict__ gates,
    unsigned short* __restrict__ a_hidden)
{
  __shared__ unsigned short lds[49152];  // 96 KiB: 2 buffers x 24576 shorts

  const int tid  = threadIdx.x;
  const int wave = tid >> 6;
  const int lane = tid & 63;
  const int wm = wave >> 2;      // 0..1 : row half (64 rows)
  const int wn = wave & 3;       // 0..3 : col quarter (64 cols)

  // XCD-aware bijective swizzle (768 % 8 == 0, cpx = 96)
  const int NWG = (B_DIM / 128) * (N1 / 256);          // 768
  const int swz = (blockIdx.x & 7) * (NWG / 8) + (blockIdx.x >> 3);
  const int ntn = N1 / 256;                            // 24
  const int tm = swz / ntn, tn = swz % ntn;
  const int tmB = tm * 128, tnB = tn * 256;

  // ---- stage source addressing (pre-swizzled global source, linear dest) ---
  const int sidx = swz1k(lane * 16);
  const int r_l  = sidx >> 6;          // row 0..15 within subtile
  const int kel  = (sidx & 63) >> 1;   // k elem offset (mult of 8)
  const unsigned short* pA[2];
  const unsigned short* pB[2];
#pragma unroll
  for (int j = 0; j < 2; ++j) {
    const int rr = wave * 16 + r_l;
    const int kk0 = j * 32 + kel;
    pA[j] = A + (size_t)(tmB + rr) * K1 + kk0;   // A tile rows 0..127
    pB[j] = W + (size_t)(tnB + rr) * K1 + kk0;   // B rows (cols of C)
  }

  // LDS (shorts): buffer p at p*24576; A at +0 (8192), B at +8192 (16384)
#define STAGE_A(tt) do { const int p_ = (tt) & 1;                                \
    gload_lds16(pA[0] + (size_t)(tt) * 64,                                       \
                &lds[p_ * 24576 + (wave * 2 + 0) * 512]);                        \
    gload_lds16(pA[1] + (size_t)(tt) * 64,                                       \
                &lds[p_ * 24576 + (wave * 2 + 1) * 512]); } while (0)
#define STAGE_B(tt, h_) do { const int p_ = (tt) & 1;                            \
    gload_lds16(pB[0] + (size_t)(h_) * 128 * K1 + (tt) * 64,                     \
                &lds[p_ * 24576 + 8192 + (h_) * 8192 + (wave * 2 + 0) * 512]);   \
    gload_lds16(pB[1] + (size_t)(h_) * 128 * K1 + (tt) * 64,                     \
                &lds[p_ * 24576 + 8192 + (h_) * 8192 + (wave * 2 + 1) * 512]); } while (0)

  // ---- ds_read addressing (R5-verified conflict-free 16x16 pattern) ----
  const int loc = swz1k((lane & 15) * 64 + (lane >> 4) * 16);

  f32x4 acc[4][4];
#pragma unroll
  for (int m = 0; m < 4; ++m)
#pragma unroll
    for (int n = 0; n < 4; ++n) acc[m][n] = (f32x4){0.f, 0.f, 0.f, 0.f};

  // prologue: tile0 A + B both halves -> 6 vmem ops
  STAGE_A(0); STAGE_B(0, 0); STAGE_B(0, 1);

#define MFMA16(aV, bV) do {                                                      \
    _Pragma("unroll")                                                            \
    for (int n = 0; n < 4; ++n) {                                                \
      _Pragma("unroll")                                                          \
      for (int m = 0; m < 4; ++m)                                                \
        acc[m][n] = __builtin_amdgcn_mfma_f32_16x16x32_bf16(                     \
            aV[m], bV[n], acc[m][n], 0, 0, 0);                                   \
    } } while (0)

  const char* lchar = (const char*)lds;
  for (int t = 0; t < NT1; ++t) {
    asm volatile("s_waitcnt vmcnt(0)" ::: "memory");
    __builtin_amdgcn_s_barrier();

    const char* base = lchar + (t & 1) * 49152;
    const char* bA = base + wm * 8192 + loc;           // 4 subtile-pairs
    const char* bB = base + 16384 + wn * 8192 + loc;   // 4 subtile-pairs

    bf16x8 a0[4], a1[4], b0[4], b1[4];
#pragma unroll
    for (int n = 0; n < 4; ++n) b0[n] = *(const bf16x8*)(bB + (2 * n + 0) * 1024);
#pragma unroll
    for (int m = 0; m < 4; ++m) a0[m] = *(const bf16x8*)(bA + (2 * m + 0) * 1024);
    if (t + 1 < NT1) STAGE_A(t + 1);
#pragma unroll
    for (int n = 0; n < 4; ++n) b1[n] = *(const bf16x8*)(bB + (2 * n + 1) * 1024);
#pragma unroll
    for (int m = 0; m < 4; ++m) a1[m] = *(const bf16x8*)(bA + (2 * m + 1) * 1024);
    if (t + 1 < NT1) { STAGE_B(t + 1, 0); STAGE_B(t + 1, 1); }

    __builtin_amdgcn_s_setprio(1);
    MFMA16(a0, b0);
    __builtin_amdgcn_s_setprio(0);
    __builtin_amdgcn_s_setprio(1);
    MFMA16(a1, b1);
    __builtin_amdgcn_s_setprio(0);
  }
#undef MFMA16
#undef STAGE_A
#undef STAGE_B

  // ---- epilogue: per-wave LDS restage -> coalesced 16B stores ----
  unsigned short* slab = &lds[wave * 1024];
  const int l15 = lane & 15, lq4 = (lane >> 4) << 2;
  const int lr8 = lane >> 3, lc8 = lane & 7;
  const bool isgate = (tn < 20);
  const int g = tn >> 2;
  const int colg0 = (isgate ? (tn & 3) : (tn - 20)) * 256 + wn * 64;
  unsigned short* outbase = isgate ? (gates + (size_t)g * ((size_t)B_DIM * 1024))
                                   : a_hidden;
  const int rowg0 = tmB + wm * 64;
  float biasv[4];
#pragma unroll
  for (int fn = 0; fn < 4; ++fn) {
    const int c = colg0 + fn * 16 + l15;
    biasv[fn] = isgate ? (bWx[g * 1024 + c] + bUx[g * 1024 + c]) : a1_b[c];
  }
  __builtin_amdgcn_s_barrier();   // all K-loop LDS traffic fully retired
#pragma unroll
  for (int fm = 0; fm < 4; ++fm) {
#pragma unroll
    for (int fn = 0; fn < 4; ++fn) {
      f32x4 v = acc[fm][fn];
#pragma unroll
      for (int j = 0; j < 4; ++j) {
        const int row = lq4 + j;
        const float xv = v[j] + biasv[fn];
        const float res = isgate ? ((g == 3) ? fast_tanh(xv) : fast_sigmoid(xv))
                                 : fmaxf(xv, 0.f);
        const int colb = ((fn * 16 + l15) * 2) ^ (((row >> 2) & 3) << 5);
        slab[(row * 128 + colb) >> 1] = f2bf(res);
      }
    }
    asm volatile("s_waitcnt lgkmcnt(0)" ::: "memory");
    __builtin_amdgcn_sched_barrier(0);
#pragma unroll
    for (int rd = 0; rd < 2; ++rd) {
      const int row = rd * 8 + lr8;
      const int cb = (lc8 * 16) ^ (((row >> 2) & 3) << 5);
      bf16x8 pk = *(const bf16x8*)((const char*)slab + row * 128 + cb);
      const size_t r = (size_t)(rowg0 + fm * 16 + row);
      *(bf16x8*)&outbase[r * 1024 + colg0 + lc8 * 8] = pk;
    }
    asm volatile("s_waitcnt lgkmcnt(0)" ::: "memory");
    __builtin_amdgcn_sched_barrier(0);
  }
}

// ---------------------------------------------------------------------------
// m97-style 128x128 GEMM for the smaller matmuls (R3 known-good version).
// MODE 1: ssg_new (fp32 -> d_out plane2) + r1 (relu->bf16); A per n-region
// MODE 2: r2 = relu(...) -> bf16
// MODE 3: residual (fp32)
// ---------------------------------------------------------------------------
template <int MODE>
__global__ __launch_bounds__(256, 3) void gemm_bf16(
    const unsigned short* __restrict__ A0g,
    const unsigned short* __restrict__ A1g,
    const unsigned short* __restrict__ Wg,
    const int M, const int N, const int K,
    const float* __restrict__ b0, const float* __restrict__ b1,
    void* __restrict__ out0, void* __restrict__ out1)
{
  __shared__ unsigned short As[128 * 64];
  __shared__ unsigned short Bs[128 * 64];

  const int tid  = threadIdx.x;
  const int wave = tid >> 6;
  const int lane = tid & 63;
  const int wm = wave >> 1, wn = wave & 1;

  const int ntn = N >> 7;
  const int tm = blockIdx.x / ntn;
  const int tn = blockIdx.x % ntn;

  const unsigned short* Ag = A0g;
  if (MODE == 1 && tn >= 8) Ag = A1g;  // n >= 1024 region uses h_prev

  const int lrow = lane >> 3;
  const int lk   = (lane & 7) * 8;
  size_t a_off[4], b_off[4];
#pragma unroll
  for (int i = 0; i < 4; ++i) {
    int c = wave * 4 + i;
    int row = c * 8 + lrow;
    a_off[i] = (size_t)(tm * 128 + row) * K + lk;
    b_off[i] = (size_t)(tn * 128 + row) * K + lk;
  }

  f32x4 acc[4][4];
#pragma unroll
  for (int m = 0; m < 4; ++m)
#pragma unroll
    for (int n = 0; n < 4; ++n) acc[m][n] = (f32x4){0.f, 0.f, 0.f, 0.f};

  const int arow  = wm * 64 + (lane & 15);
  const int brow  = wn * 64 + (lane & 15);
  const int kfrag = (lane >> 4) * 8;

  for (int k0 = 0; k0 < K; k0 += 64) {
#pragma unroll
    for (int i = 0; i < 4; ++i) {
      gload_lds16(Ag + a_off[i] + k0, &As[(wave * 4 + i) * 512]);
      gload_lds16(Wg + b_off[i] + k0, &Bs[(wave * 4 + i) * 512]);
    }
    __syncthreads();
#pragma unroll
    for (int kk = 0; kk < 2; ++kk) {
      bf16x8 af[4], bfr[4];
#pragma unroll
      for (int m = 0; m < 4; ++m)
        af[m] = *(const bf16x8*)&As[(arow + m * 16) * 64 + kk * 32 + kfrag];
#pragma unroll
      for (int n = 0; n < 4; ++n)
        bfr[n] = *(const bf16x8*)&Bs[(brow + n * 16) * 64 + kk * 32 + kfrag];
#pragma unroll
      for (int m = 0; m < 4; ++m)
#pragma unroll
        for (int n = 0; n < 4; ++n)
          acc[m][n] = __builtin_amdgcn_mfma_f32_16x16x32_bf16(
              af[m], bfr[n], acc[m][n], 0, 0, 0);
    }
    __syncthreads();
  }

  const int col0 = tn * 128 + wn * 64;
  const int row0 = tm * 128 + wm * 64 + ((lane >> 4) << 2);
#pragma unroll
  for (int n = 0; n < 4; ++n) {
    const int col = col0 + n * 16 + (lane & 15);
    float bias;
    if (MODE == 1)      bias = (col < 1024) ? b0[col] : b1[col - 1024];
    else                bias = b0[col];
#pragma unroll
    for (int m = 0; m < 4; ++m) {
      const int rowb = row0 + m * 16;
      f32x4 v = acc[m][n];
#pragma unroll
      for (int j = 0; j < 4; ++j) {
        const float xv = v[j] + bias;
        const int r = rowb + j;
        if (MODE == 1) {
          if (col < 1024) {
            ((float*)out0)[(size_t)r * 1024 + col] = xv;             // ssg_new fp32
          } else {
            ((unsigned short*)out1)[(size_t)r * 1024 + (col - 1024)] = f2bf(fmaxf(xv, 0.f));
          }
        } else if (MODE == 2) {
          ((unsigned short*)out0)[(size_t)r * 1024 + col] = f2bf(fmaxf(xv, 0.f));
        } else {
          ((float*)out0)[(size_t)r * 1024 + col] = xv;               // residual fp32
        }
      }
    }
  }
}

// ---------------------------------------------------------------------------
// alpha GEMV
// ---------------------------------------------------------------------------
__global__ __launch_bounds__(256) void alpha_kernel(
    const unsigned short* __restrict__ a_hidden,
    const float* __restrict__ a2_w, const float* __restrict__ a2_b,
    float* __restrict__ alpha)
{
  const int wave = threadIdx.x >> 6, lane = threadIdx.x & 63;
  const int row = blockIdx.x * 4 + wave;
  const unsigned short* ah = a_hidden + (size_t)row * 1024;
  float sum = 0.f;
#pragma unroll
  for (int half = 0; half < 2; ++half) {
    const int h0 = half * 512 + lane * 8;
    ushort4 u0 = *(const ushort4*)&ah[h0];
    ushort4 u1 = *(const ushort4*)&ah[h0 + 4];
    float4 w0 = *(const float4*)&a2_w[h0];
    float4 w1 = *(const float4*)&a2_w[h0 + 4];
    sum += bf2f(u0.x) * w0.x + bf2f(u0.y) * w0.y + bf2f(u0.z) * w0.z + bf2f(u0.w) * w0.w;
    sum += bf2f(u1.x) * w1.x + bf2f(u1.y) * w1.y + bf2f(u1.z) * w1.z + bf2f(u1.w) * w1.w;
  }
#pragma unroll
  for (int off = 32; off; off >>= 1) sum += __shfl_xor(sum, off);
  if (lane == 0) alpha[row] = fast_sigmoid(sum + a2_b[0]);
}

// ---------------------------------------------------------------------------
// final elementwise (high-occupancy vec4 streaming)
// ---------------------------------------------------------------------------
__global__ __launch_bounds__(256) void final_elem_kernel(
    const unsigned short* __restrict__ gates,
    const float* __restrict__ c_prev,
    const float* __restrict__ alpha,
    const float* __restrict__ residual,
    const float* __restrict__ ssg_new,
    float* __restrict__ h_out, float* __restrict__ c_out)
{
  const size_t BH = (size_t)B_DIM * H_DIM;
  const size_t e = ((size_t)blockIdx.x * blockDim.x + threadIdx.x) * 4;
  if (e >= BH) return;
  const float al = alpha[e >> 10];
  ushort4 iu = *(const ushort4*)&gates[e];
  ushort4 fu = *(const ushort4*)&gates[BH + e];
  ushort4 ou = *(const ushort4*)&gates[2 * BH + e];
  ushort4 cu = *(const ushort4*)&gates[3 * BH + e];
  ushort4 su = *(const ushort4*)&gates[4 * BH + e];
  float4 cp = *(const float4*)&c_prev[e];
  float4 rs = *(const float4*)&residual[e];
  float4 sg = *(const float4*)&ssg_new[e];
  float4 ho, co;
  co.x = bf2f(fu.x) * cp.x + bf2f(iu.x) * bf2f(cu.x) * bf2f(su.x) * al * sg.x + rs.x;
  co.y = bf2f(fu.y) * cp.y + bf2f(iu.y) * bf2f(cu.y) * bf2f(su.y) * al * sg.y + rs.y;
  co.z = bf2f(fu.z) * cp.z + bf2f(iu.z) * bf2f(cu.z) * bf2f(su.z) * al * sg.z + rs.z;
  co.w = bf2f(fu.w) * cp.w + bf2f(iu.w) * bf2f(cu.w) * bf2f(su.w) * al * sg.w + rs.w;
  ho.x = bf2f(ou.x) * fast_tanh(co.x);
  ho.y = bf2f(ou.y) * fast_tanh(co.y);
  ho.z = bf2f(ou.z) * fast_tanh(co.z);
  ho.w = bf2f(ou.w) * fast_tanh(co.w);
  *(float4*)&h_out[e] = ho;
  *(float4*)&c_out[e] = co;
}

// ---------------------------------------------------------------------------
extern "C" void kernel_launch(void* const* d_in, const int* in_sizes, int n_in,
                              void* d_out, int out_size, void* d_ws, size_t ws_size,
                              hipStream_t stream)
{
  (void)in_sizes; (void)n_in; (void)out_size; (void)ws_size;
  const float* x         = (const float*)d_in[0];
  const float* h_prev    = (const float*)d_in[1];
  const float* c_prev    = (const float*)d_in[2];
  const float* ssg_state = (const float*)d_in[3];
  const float* Wx        = (const float*)d_in[4];
  const float* bWx       = (const float*)d_in[5];
  const float* Ux        = (const float*)d_in[6];
  const float* bUx       = (const float*)d_in[7];
  const float* a1_w      = (const float*)d_in[8];
  const float* a1_b      = (const float*)d_in[9];
  const float* a2_w      = (const float*)d_in[10];
  const float* a2_b      = (const float*)d_in[11];
  const float* r1_w      = (const float*)d_in[12];
  const float* r1_b      = (const float*)d_in[13];
  const float* r2_w      = (const float*)d_in[14];
  const float* r2_b      = (const float*)d_in[15];
  const float* r3_w      = (const float*)d_in[16];
  const float* r3_b      = (const float*)d_in[17];
  const float* ssg_w     = (const float*)d_in[18];
  const float* ssg_b     = (const float*)d_in[19];

  char* ws = (char*)d_ws;
  unsigned short* combined = (unsigned short*)(ws);               // 16,777,216
  unsigned short* ssg_in   = (unsigned short*)(ws + 16777216);    //  8,388,608
  unsigned short* hprev_bf = (unsigned short*)(ws + 25165824);    //  8,388,608
  unsigned short* W1       = (unsigned short*)(ws + 33554432);    // 25,165,824
  unsigned short* W2       = (unsigned short*)(ws + 58720256);    //  4,194,304
  unsigned short* W3       = (unsigned short*)(ws + 62914560);    //  2,097,152
  unsigned short* W4       = (unsigned short*)(ws + 65011712);    //  2,097,152
  unsigned short* gates    = (unsigned short*)(ws + 67108864);    // 41,943,040
  unsigned short* a_hidden = (unsigned short*)(ws + 109051904);   //  8,388,608
  float*          alpha    = (float*)(ws + 117440512);            //     16,384
  unsigned short* r1       = (unsigned short*)(ws + 117456896);   //  8,388,608
  unsigned short* r2       = (unsigned short*)(ws + 125845504);   //  8,388,608
  float*          residual = (float*)(ws + 134234112);            // 16,777,216

  float* h_out   = (float*)d_out;
  float* c_out   = h_out + (size_t)B_DIM * H_DIM;
  float* ssg_out = c_out + (size_t)B_DIM * H_DIM;

  prep_kernel<<<4096, 256, 0, stream>>>(x, h_prev, ssg_state, Wx, Ux, a1_w,
                                        ssg_w, r1_w, r2_w, r3_w,
                                        combined, ssg_in, hprev_bf, W1, W2, W3, W4);

  gemm8p_mode0<<<(B_DIM / 128) * (N1 / 256), 512, 0, stream>>>(
      combined, W1, bWx, bUx, a1_b, gates, a_hidden);

  gemm_bf16<1><<<(B_DIM / 128) * (N2 / 128), 256, 0, stream>>>(
      ssg_in, hprev_bf, W2, B_DIM, N2, 1024, ssg_b, r1_b, ssg_out, r1);

  gemm_bf16<2><<<(B_DIM / 128) * (1024 / 128), 256, 0, stream>>>(
      r1, r1, W3, B_DIM, 1024, 1024, r2_b, nullptr, r2, nullptr);

  gemm_bf16<3><<<(B_DIM / 128) * (1024 / 128), 256, 0, stream>>>(
      r2, r2, W4, B_DIM, 1024, 1024, r3_b, nullptr, residual, nullptr);

  alpha_kernel<<<B_DIM / 4, 256, 0, stream>>>(a_hidden, a2_w, a2_b, alpha);

  final_elem_kernel<<<(B_DIM * H_DIM / 4) / 256, 256, 0, stream>>>(
      gates, c_prev, alpha, residual, ssg_out, h_out, c_out);
}

// Round 9
// 254.165 us; speedup vs baseline: 1.0616x; 1.0616x over previous
//
#include <hip/hip_runtime.h>
#include <hip/hip_bf16.h>

// Problem constants
#define B_DIM 4096
#define H_DIM 1024
#define K1    2048   // IN + H
#define N1    6144   // 5 gates * 1024 + a1 (1024)
#define NT1   (K1 / 64)   // 32 K-tiles for the big GEMM
#define NT2   16          // K=1024 tiles for gemm_n2048

typedef __attribute__((ext_vector_type(8))) short bf16x8;
typedef __attribute__((ext_vector_type(4))) float f32x4;

__device__ __forceinline__ unsigned short f2bf(float f) {
  unsigned int x = __float_as_uint(f);
  x += 0x7fffu + ((x >> 16) & 1u);   // RTNE
  return (unsigned short)(x >> 16);
}
__device__ __forceinline__ float bf2f(unsigned short u) {
  return __uint_as_float(((unsigned int)u) << 16);
}
__device__ __forceinline__ float fast_sigmoid(float x) {
  return __builtin_amdgcn_rcpf(1.0f + __expf(-x));
}
__device__ __forceinline__ float fast_tanh(float x) {
  return 1.0f - 2.0f * __builtin_amdgcn_rcpf(1.0f + __expf(2.0f * x));
}
__device__ __forceinline__ void gload_lds16(const void* g, void* l) {
  __builtin_amdgcn_global_load_lds(
      (const __attribute__((address_space(1))) void*)g,
      (__attribute__((address_space(3))) void*)l, 16, 0, 0);
}

// m201's st_16x32 swizzle: XOR byte-bit5 with bit9 within a 1024B subtile.
__device__ __forceinline__ int swz1k(int x) {
  return x ^ (((x >> 9) & 1) << 5);
}

// ---------------------------------------------------------------------------
// prep: build bf16 activations + weight panels in workspace (grid-stride vec4)
// (hprev_bf dropped: gemm_n2048 reads h via combined+1024, lda 2048)
// ---------------------------------------------------------------------------
__global__ __launch_bounds__(256) void prep_kernel(
    const float* __restrict__ x, const float* __restrict__ h,
    const float* __restrict__ ssg_state,
    const float* __restrict__ Wx, const float* __restrict__ Ux,
    const float* __restrict__ a1_w,
    const float* __restrict__ ssg_w, const float* __restrict__ r1_w,
    const float* __restrict__ r2_w, const float* __restrict__ r3_w,
    unsigned short* __restrict__ combined,
    unsigned short* __restrict__ ssg_in,
    unsigned short* __restrict__ W1,
    unsigned short* __restrict__ W2,
    unsigned short* __restrict__ W3,
    unsigned short* __restrict__ W4)
{
  const size_t NV0 = (size_t)B_DIM * K1 / 4;      // combined
  const size_t NV1 = (size_t)B_DIM * H_DIM / 4;   // ssg_in
  const size_t NV3 = (size_t)N1 * K1 / 4;         // W1
  const size_t NV4 = (size_t)2048 * H_DIM / 4;    // W2
  const size_t NV5 = (size_t)H_DIM * H_DIM / 4;   // W3, W4
  const size_t total = NV0 + NV1 + NV3 + NV4 + NV5 + NV5;
  const size_t stride = (size_t)gridDim.x * blockDim.x;

  for (size_t v = (size_t)blockIdx.x * blockDim.x + threadIdx.x; v < total; v += stride) {
    size_t idx = v;
    const float* src;
    unsigned short* dst;
    if (idx < NV0) {
      size_t e = idx * 4, b = e >> 11, k = e & 2047;
      src = (k < 1024) ? &x[(b << 10) + k] : &h[(b << 10) + (k - 1024)];
      dst = &combined[e];
    } else if ((idx -= NV0) < NV1) {
      size_t e = idx * 4;
      float4 a = *(const float4*)&ssg_state[e];
      float4 c = *(const float4*)&h[e];
      ushort4 o;
      o.x = f2bf(a.x + c.x); o.y = f2bf(a.y + c.y);
      o.z = f2bf(a.z + c.z); o.w = f2bf(a.w + c.w);
      *(ushort4*)&ssg_in[e] = o;
      continue;
    } else if ((idx -= NV1) < NV3) {
      size_t e = idx * 4, n = e >> 11, k = e & 2047;
      if (n < 5120) src = (k < 1024) ? &Wx[(n << 10) + k] : &Ux[(n << 10) + (k - 1024)];
      else          src = &a1_w[((n - 5120) << 11) + k];
      dst = &W1[e];
    } else if ((idx -= NV3) < NV4) {
      size_t e = idx * 4, n = e >> 10, k = e & 1023;
      src = (n < 1024) ? &ssg_w[(n << 10) + k] : &r1_w[((n - 1024) << 10) + k];
      dst = &W2[e];
    } else if ((idx -= NV4) < NV5) {
      size_t e = idx * 4; src = &r2_w[e]; dst = &W3[e];
    } else {
      idx -= NV5;
      size_t e = idx * 4; src = &r3_w[e]; dst = &W4[e];
    }
    float4 a = *(const float4*)src;
    ushort4 o;
    o.x = f2bf(a.x); o.y = f2bf(a.y); o.z = f2bf(a.z); o.w = f2bf(a.w);
    *(ushort4*)dst = o;
  }
}

// ---------------------------------------------------------------------------
// 128x256 GEMM, one-barrier-per-K-tile (R8 verified structure, unchanged).
// ---------------------------------------------------------------------------
__global__ __launch_bounds__(512, 2) void gemm8p_mode0(
    const unsigned short* __restrict__ A,
    const unsigned short* __restrict__ W,
    const float* __restrict__ bWx, const float* __restrict__ bUx,
    const float* __restrict__ a1_b,
    unsigned short* __restrict__ gates,
    unsigned short* __restrict__ a_hidden)
{
  __shared__ unsigned short lds[49152];  // 96 KiB: 2 buffers x 24576 shorts

  const int tid  = threadIdx.x;
  const int wave = tid >> 6;
  const int lane = tid & 63;
  const int wm = wave >> 2;
  const int wn = wave & 3;

  const int NWG = (B_DIM / 128) * (N1 / 256);          // 768
  const int swz = (blockIdx.x & 7) * (NWG / 8) + (blockIdx.x >> 3);
  const int ntn = N1 / 256;                            // 24
  const int tm = swz / ntn, tn = swz % ntn;
  const int tmB = tm * 128, tnB = tn * 256;

  const int sidx = swz1k(lane * 16);
  const int r_l  = sidx >> 6;
  const int kel  = (sidx & 63) >> 1;
  const unsigned short* pA[2];
  const unsigned short* pB[2];
#pragma unroll
  for (int j = 0; j < 2; ++j) {
    const int rr = wave * 16 + r_l;
    const int kk0 = j * 32 + kel;
    pA[j] = A + (size_t)(tmB + rr) * K1 + kk0;
    pB[j] = W + (size_t)(tnB + rr) * K1 + kk0;
  }

#define STAGE_A(tt) do { const int p_ = (tt) & 1;                                \
    gload_lds16(pA[0] + (size_t)(tt) * 64,                                       \
                &lds[p_ * 24576 + (wave * 2 + 0) * 512]);                        \
    gload_lds16(pA[1] + (size_t)(tt) * 64,                                       \
                &lds[p_ * 24576 + (wave * 2 + 1) * 512]); } while (0)
#define STAGE_B(tt, h_) do { const int p_ = (tt) & 1;                            \
    gload_lds16(pB[0] + (size_t)(h_) * 128 * K1 + (tt) * 64,                     \
                &lds[p_ * 24576 + 8192 + (h_) * 8192 + (wave * 2 + 0) * 512]);   \
    gload_lds16(pB[1] + (size_t)(h_) * 128 * K1 + (tt) * 64,                     \
                &lds[p_ * 24576 + 8192 + (h_) * 8192 + (wave * 2 + 1) * 512]); } while (0)

  const int loc = swz1k((lane & 15) * 64 + (lane >> 4) * 16);

  f32x4 acc[4][4];
#pragma unroll
  for (int m = 0; m < 4; ++m)
#pragma unroll
    for (int n = 0; n < 4; ++n) acc[m][n] = (f32x4){0.f, 0.f, 0.f, 0.f};

  STAGE_A(0); STAGE_B(0, 0); STAGE_B(0, 1);

#define MFMA16(aV, bV) do {                                                      \
    _Pragma("unroll")                                                            \
    for (int n = 0; n < 4; ++n) {                                                \
      _Pragma("unroll")                                                          \
      for (int m = 0; m < 4; ++m)                                                \
        acc[m][n] = __builtin_amdgcn_mfma_f32_16x16x32_bf16(                     \
            aV[m], bV[n], acc[m][n], 0, 0, 0);                                   \
    } } while (0)

  const char* lchar = (const char*)lds;
  for (int t = 0; t < NT1; ++t) {
    asm volatile("s_waitcnt vmcnt(0)" ::: "memory");
    __builtin_amdgcn_s_barrier();

    const char* base = lchar + (t & 1) * 49152;
    const char* bA = base + wm * 8192 + loc;
    const char* bB = base + 16384 + wn * 8192 + loc;

    bf16x8 a0[4], a1[4], b0[4], b1[4];
#pragma unroll
    for (int n = 0; n < 4; ++n) b0[n] = *(const bf16x8*)(bB + (2 * n + 0) * 1024);
#pragma unroll
    for (int m = 0; m < 4; ++m) a0[m] = *(const bf16x8*)(bA + (2 * m + 0) * 1024);
    if (t + 1 < NT1) STAGE_A(t + 1);
#pragma unroll
    for (int n = 0; n < 4; ++n) b1[n] = *(const bf16x8*)(bB + (2 * n + 1) * 1024);
#pragma unroll
    for (int m = 0; m < 4; ++m) a1[m] = *(const bf16x8*)(bA + (2 * m + 1) * 1024);
    if (t + 1 < NT1) { STAGE_B(t + 1, 0); STAGE_B(t + 1, 1); }

    __builtin_amdgcn_s_setprio(1);
    MFMA16(a0, b0);
    __builtin_amdgcn_s_setprio(0);
    __builtin_amdgcn_s_setprio(1);
    MFMA16(a1, b1);
    __builtin_amdgcn_s_setprio(0);
  }
#undef MFMA16
#undef STAGE_A
#undef STAGE_B

  // epilogue: per-wave LDS restage -> coalesced 16B stores
  unsigned short* slab = &lds[wave * 1024];
  const int l15 = lane & 15, lq4 = (lane >> 4) << 2;
  const int lr8 = lane >> 3, lc8 = lane & 7;
  const bool isgate = (tn < 20);
  const int g = tn >> 2;
  const int colg0 = (isgate ? (tn & 3) : (tn - 20)) * 256 + wn * 64;
  unsigned short* outbase = isgate ? (gates + (size_t)g * ((size_t)B_DIM * 1024))
                                   : a_hidden;
  const int rowg0 = tmB + wm * 64;
  float biasv[4];
#pragma unroll
  for (int fn = 0; fn < 4; ++fn) {
    const int c = colg0 + fn * 16 + l15;
    biasv[fn] = isgate ? (bWx[g * 1024 + c] + bUx[g * 1024 + c]) : a1_b[c];
  }
  __builtin_amdgcn_s_barrier();
#pragma unroll
  for (int fm = 0; fm < 4; ++fm) {
#pragma unroll
    for (int fn = 0; fn < 4; ++fn) {
      f32x4 v = acc[fm][fn];
#pragma unroll
      for (int j = 0; j < 4; ++j) {
        const int row = lq4 + j;
        const float xv = v[j] + biasv[fn];
        const float res = isgate ? ((g == 3) ? fast_tanh(xv) : fast_sigmoid(xv))
                                 : fmaxf(xv, 0.f);
        const int colb = ((fn * 16 + l15) * 2) ^ (((row >> 2) & 3) << 5);
        slab[(row * 128 + colb) >> 1] = f2bf(res);
      }
    }
    asm volatile("s_waitcnt lgkmcnt(0)" ::: "memory");
    __builtin_amdgcn_sched_barrier(0);
#pragma unroll
    for (int rd = 0; rd < 2; ++rd) {
      const int row = rd * 8 + lr8;
      const int cb = (lc8 * 16) ^ (((row >> 2) & 3) << 5);
      bf16x8 pk = *(const bf16x8*)((const char*)slab + row * 128 + cb);
      const size_t r = (size_t)(rowg0 + fm * 16 + row);
      *(bf16x8*)&outbase[r * 1024 + colg0 + lc8 * 8] = pk;
    }
    asm volatile("s_waitcnt lgkmcnt(0)" ::: "memory");
    __builtin_amdgcn_sched_barrier(0);
  }
}

// ---------------------------------------------------------------------------
// gemm_n2048: [4096 x 2048] = A @ W2^T, K=1024, R8 structure, grid 256 =
// exactly one full round. tn<4: A=ssg_in (lda 1024) -> ssg_new fp32;
// tn>=4: A=combined+1024 (lda 2048, h rows) -> r1 = relu -> bf16 slab.
// ---------------------------------------------------------------------------
__global__ __launch_bounds__(512, 2) void gemm_n2048(
    const unsigned short* __restrict__ A0,
    const unsigned short* __restrict__ A1,
    const unsigned short* __restrict__ W,
    const float* __restrict__ ssg_b, const float* __restrict__ r1_b,
    float* __restrict__ ssg_out,
    unsigned short* __restrict__ r1)
{
  __shared__ unsigned short lds[49152];

  const int tid  = threadIdx.x;
  const int wave = tid >> 6;
  const int lane = tid & 63;
  const int wm = wave >> 2;
  const int wn = wave & 3;

  const int swz = (blockIdx.x & 7) * 32 + (blockIdx.x >> 3);   // NWG=256
  const int tm = swz >> 3, tn = swz & 7;
  const int tmB = tm * 128, tnB = tn * 256;

  const unsigned short* Abase = (tn < 4) ? A0 : A1;
  const int lda = (tn < 4) ? 1024 : 2048;

  const int sidx = swz1k(lane * 16);
  const int r_l  = sidx >> 6;
  const int kel  = (sidx & 63) >> 1;
  const unsigned short* pA[2];
  const unsigned short* pB[2];
#pragma unroll
  for (int j = 0; j < 2; ++j) {
    const int rr = wave * 16 + r_l;
    const int kk0 = j * 32 + kel;
    pA[j] = Abase + (size_t)(tmB + rr) * lda + kk0;
    pB[j] = W + (size_t)(tnB + rr) * 1024 + kk0;
  }

#define STAGE_A(tt) do { const int p_ = (tt) & 1;                                \
    gload_lds16(pA[0] + (size_t)(tt) * 64,                                       \
                &lds[p_ * 24576 + (wave * 2 + 0) * 512]);                        \
    gload_lds16(pA[1] + (size_t)(tt) * 64,                                       \
                &lds[p_ * 24576 + (wave * 2 + 1) * 512]); } while (0)
#define STAGE_B(tt, h_) do { const int p_ = (tt) & 1;                            \
    gload_lds16(pB[0] + (size_t)(h_) * 128 * 1024 + (tt) * 64,                   \
                &lds[p_ * 24576 + 8192 + (h_) * 8192 + (wave * 2 + 0) * 512]);   \
    gload_lds16(pB[1] + (size_t)(h_) * 128 * 1024 + (tt) * 64,                   \
                &lds[p_ * 24576 + 8192 + (h_) * 8192 + (wave * 2 + 1) * 512]); } while (0)

  const int loc = swz1k((lane & 15) * 64 + (lane >> 4) * 16);

  f32x4 acc[4][4];
#pragma unroll
  for (int m = 0; m < 4; ++m)
#pragma unroll
    for (int n = 0; n < 4; ++n) acc[m][n] = (f32x4){0.f, 0.f, 0.f, 0.f};

  STAGE_A(0); STAGE_B(0, 0); STAGE_B(0, 1);

#define MFMA16(aV, bV) do {                                                      \
    _Pragma("unroll")                                                            \
    for (int n = 0; n < 4; ++n) {                                                \
      _Pragma("unroll")                                                          \
      for (int m = 0; m < 4; ++m)                                                \
        acc[m][n] = __builtin_amdgcn_mfma_f32_16x16x32_bf16(                     \
            aV[m], bV[n], acc[m][n], 0, 0, 0);                                   \
    } } while (0)

  const char* lchar = (const char*)lds;
  for (int t = 0; t < NT2; ++t) {
    asm volatile("s_waitcnt vmcnt(0)" ::: "memory");
    __builtin_amdgcn_s_barrier();

    const char* base = lchar + (t & 1) * 49152;
    const char* bA = base + wm * 8192 + loc;
    const char* bB = base + 16384 + wn * 8192 + loc;

    bf16x8 a0[4], a1[4], b0[4], b1[4];
#pragma unroll
    for (int n = 0; n < 4; ++n) b0[n] = *(const bf16x8*)(bB + (2 * n + 0) * 1024);
#pragma unroll
    for (int m = 0; m < 4; ++m) a0[m] = *(const bf16x8*)(bA + (2 * m + 0) * 1024);
    if (t + 1 < NT2) STAGE_A(t + 1);
#pragma unroll
    for (int n = 0; n < 4; ++n) b1[n] = *(const bf16x8*)(bB + (2 * n + 1) * 1024);
#pragma unroll
    for (int m = 0; m < 4; ++m) a1[m] = *(const bf16x8*)(bA + (2 * m + 1) * 1024);
    if (t + 1 < NT2) { STAGE_B(t + 1, 0); STAGE_B(t + 1, 1); }

    __builtin_amdgcn_s_setprio(1);
    MFMA16(a0, b0);
    __builtin_amdgcn_s_setprio(0);
    __builtin_amdgcn_s_setprio(1);
    MFMA16(a1, b1);
    __builtin_amdgcn_s_setprio(0);
  }
#undef MFMA16
#undef STAGE_A
#undef STAGE_B

  const int l15 = lane & 15, lq4 = (lane >> 4) << 2;
  const int rowg0 = tmB + wm * 64;
  if (tn < 4) {
    // ssg_new fp32 direct stores
    const int col0 = tn * 256 + wn * 64;
#pragma unroll
    for (int fn = 0; fn < 4; ++fn) {
      const int col = col0 + fn * 16 + l15;
      const float bias = ssg_b[col];
#pragma unroll
      for (int fm = 0; fm < 4; ++fm) {
        f32x4 v = acc[fm][fn];
#pragma unroll
        for (int j = 0; j < 4; ++j) {
          const int r = rowg0 + fm * 16 + lq4 + j;
          ssg_out[(size_t)r * 1024 + col] = v[j] + bias;
        }
      }
    }
  } else {
    // r1 = relu -> bf16, slab restage for coalesced 16B stores
    unsigned short* slab = &lds[wave * 1024];
    const int lr8 = lane >> 3, lc8 = lane & 7;
    const int colg0 = (tn - 4) * 256 + wn * 64;
    float biasv[4];
#pragma unroll
    for (int fn = 0; fn < 4; ++fn) biasv[fn] = r1_b[colg0 + fn * 16 + l15];
    __builtin_amdgcn_s_barrier();
#pragma unroll
    for (int fm = 0; fm < 4; ++fm) {
#pragma unroll
      for (int fn = 0; fn < 4; ++fn) {
        f32x4 v = acc[fm][fn];
#pragma unroll
        for (int j = 0; j < 4; ++j) {
          const int row = lq4 + j;
          const float res = fmaxf(v[j] + biasv[fn], 0.f);
          const int colb = ((fn * 16 + l15) * 2) ^ (((row >> 2) & 3) << 5);
          slab[(row * 128 + colb) >> 1] = f2bf(res);
        }
      }
      asm volatile("s_waitcnt lgkmcnt(0)" ::: "memory");
      __builtin_amdgcn_sched_barrier(0);
#pragma unroll
      for (int rd = 0; rd < 2; ++rd) {
        const int row = rd * 8 + lr8;
        const int cb = (lc8 * 16) ^ (((row >> 2) & 3) << 5);
        bf16x8 pk = *(const bf16x8*)((const char*)slab + row * 128 + cb);
        const size_t r = (size_t)(rowg0 + fm * 16 + row);
        *(bf16x8*)&r1[r * 1024 + colg0 + lc8 * 8] = pk;
      }
      asm volatile("s_waitcnt lgkmcnt(0)" ::: "memory");
      __builtin_amdgcn_sched_barrier(0);
    }
  }
}

// ---------------------------------------------------------------------------
// m97-style 128x128 GEMM (modes 2, 3 only).
// ---------------------------------------------------------------------------
template <int MODE>
__global__ __launch_bounds__(256, 3) void gemm_bf16(
    const unsigned short* __restrict__ A0g,
    const unsigned short* __restrict__ Wg,
    const int M, const int N, const int K,
    const float* __restrict__ b0,
    void* __restrict__ out0)
{
  __shared__ unsigned short As[128 * 64];
  __shared__ unsigned short Bs[128 * 64];

  const int tid  = threadIdx.x;
  const int wave = tid >> 6;
  const int lane = tid & 63;
  const int wm = wave >> 1, wn = wave & 1;

  const int ntn = N >> 7;
  const int tm = blockIdx.x / ntn;
  const int tn = blockIdx.x % ntn;

  const int lrow = lane >> 3;
  const int lk   = (lane & 7) * 8;
  size_t a_off[4], b_off[4];
#pragma unroll
  for (int i = 0; i < 4; ++i) {
    int c = wave * 4 + i;
    int row = c * 8 + lrow;
    a_off[i] = (size_t)(tm * 128 + row) * K + lk;
    b_off[i] = (size_t)(tn * 128 + row) * K + lk;
  }

  f32x4 acc[4][4];
#pragma unroll
  for (int m = 0; m < 4; ++m)
#pragma unroll
    for (int n = 0; n < 4; ++n) acc[m][n] = (f32x4){0.f, 0.f, 0.f, 0.f};

  const int arow  = wm * 64 + (lane & 15);
  const int brow  = wn * 64 + (lane & 15);
  const int kfrag = (lane >> 4) * 8;

  for (int k0 = 0; k0 < K; k0 += 64) {
#pragma unroll
    for (int i = 0; i < 4; ++i) {
      gload_lds16(A0g + a_off[i] + k0, &As[(wave * 4 + i) * 512]);
      gload_lds16(Wg + b_off[i] + k0, &Bs[(wave * 4 + i) * 512]);
    }
    __syncthreads();
#pragma unroll
    for (int kk = 0; kk < 2; ++kk) {
      bf16x8 af[4], bfr[4];
#pragma unroll
      for (int m = 0; m < 4; ++m)
        af[m] = *(const bf16x8*)&As[(arow + m * 16) * 64 + kk * 32 + kfrag];
#pragma unroll
      for (int n = 0; n < 4; ++n)
        bfr[n] = *(const bf16x8*)&Bs[(brow + n * 16) * 64 + kk * 32 + kfrag];
#pragma unroll
      for (int m = 0; m < 4; ++m)
#pragma unroll
        for (int n = 0; n < 4; ++n)
          acc[m][n] = __builtin_amdgcn_mfma_f32_16x16x32_bf16(
              af[m], bfr[n], acc[m][n], 0, 0, 0);
    }
    __syncthreads();
  }

  const int col0 = tn * 128 + wn * 64;
  const int row0 = tm * 128 + wm * 64 + ((lane >> 4) << 2);
#pragma unroll
  for (int n = 0; n < 4; ++n) {
    const int col = col0 + n * 16 + (lane & 15);
    const float bias = b0[col];
#pragma unroll
    for (int m = 0; m < 4; ++m) {
      const int rowb = row0 + m * 16;
      f32x4 v = acc[m][n];
#pragma unroll
      for (int j = 0; j < 4; ++j) {
        const float xv = v[j] + bias;
        const int r = rowb + j;
        if (MODE == 2) {
          ((unsigned short*)out0)[(size_t)r * 1024 + col] = f2bf(fmaxf(xv, 0.f));
        } else {
          ((float*)out0)[(size_t)r * 1024 + col] = xv;               // residual fp32
        }
      }
    }
  }
}

// ---------------------------------------------------------------------------
// final fused: per-row alpha (4-wave reduce) + vec4 elementwise cell update.
// One block per batch row (grid 4096, block 256).
// ---------------------------------------------------------------------------
__global__ __launch_bounds__(256) void final_fused(
    const unsigned short* __restrict__ gates,
    const float* __restrict__ c_prev,
    const unsigned short* __restrict__ a_hidden,
    const float* __restrict__ a2_w, const float* __restrict__ a2_b,
    const float* __restrict__ residual,
    const float* __restrict__ ssg_new,
    float* __restrict__ h_out, float* __restrict__ c_out)
{
  __shared__ float red[5];
  const int r = blockIdx.x;
  const int tid = threadIdx.x;
  const size_t BH = (size_t)B_DIM * H_DIM;

  // alpha = sigmoid(dot(a_hidden[r,:], a2_w) + a2_b)
  {
    ushort4 u = *(const ushort4*)&a_hidden[(size_t)r * 1024 + tid * 4];
    float4 w = *(const float4*)&a2_w[tid * 4];
    float s = bf2f(u.x) * w.x + bf2f(u.y) * w.y + bf2f(u.z) * w.z + bf2f(u.w) * w.w;
#pragma unroll
    for (int off = 32; off; off >>= 1) s += __shfl_xor(s, off);
    if ((tid & 63) == 0) red[tid >> 6] = s;
  }
  __syncthreads();
  if (tid == 0)
    red[4] = fast_sigmoid(red[0] + red[1] + red[2] + red[3] + a2_b[0]);
  __syncthreads();
  const float al = red[4];

  const size_t e = (size_t)r * 1024 + tid * 4;
  ushort4 iu = *(const ushort4*)&gates[e];
  ushort4 fu = *(const ushort4*)&gates[BH + e];
  ushort4 ou = *(const ushort4*)&gates[2 * BH + e];
  ushort4 cu = *(const ushort4*)&gates[3 * BH + e];
  ushort4 su = *(const ushort4*)&gates[4 * BH + e];
  float4 cp = *(const float4*)&c_prev[e];
  float4 rs = *(const float4*)&residual[e];
  float4 sg = *(const float4*)&ssg_new[e];
  float4 ho, co;
  co.x = bf2f(fu.x) * cp.x + bf2f(iu.x) * bf2f(cu.x) * bf2f(su.x) * al * sg.x + rs.x;
  co.y = bf2f(fu.y) * cp.y + bf2f(iu.y) * bf2f(cu.y) * bf2f(su.y) * al * sg.y + rs.y;
  co.z = bf2f(fu.z) * cp.z + bf2f(iu.z) * bf2f(cu.z) * bf2f(su.z) * al * sg.z + rs.z;
  co.w = bf2f(fu.w) * cp.w + bf2f(iu.w) * bf2f(cu.w) * bf2f(su.w) * al * sg.w + rs.w;
  ho.x = bf2f(ou.x) * fast_tanh(co.x);
  ho.y = bf2f(ou.y) * fast_tanh(co.y);
  ho.z = bf2f(ou.z) * fast_tanh(co.z);
  ho.w = bf2f(ou.w) * fast_tanh(co.w);
  *(float4*)&h_out[e] = ho;
  *(float4*)&c_out[e] = co;
}

// ---------------------------------------------------------------------------
extern "C" void kernel_launch(void* const* d_in, const int* in_sizes, int n_in,
                              void* d_out, int out_size, void* d_ws, size_t ws_size,
                              hipStream_t stream)
{
  (void)in_sizes; (void)n_in; (void)out_size; (void)ws_size;
  const float* x         = (const float*)d_in[0];
  const float* h_prev    = (const float*)d_in[1];
  const float* c_prev    = (const float*)d_in[2];
  const float* ssg_state = (const float*)d_in[3];
  const float* Wx        = (const float*)d_in[4];
  const float* bWx       = (const float*)d_in[5];
  const float* Ux        = (const float*)d_in[6];
  const float* bUx       = (const float*)d_in[7];
  const float* a1_w      = (const float*)d_in[8];
  const float* a1_b      = (const float*)d_in[9];
  const float* a2_w      = (const float*)d_in[10];
  const float* a2_b      = (const float*)d_in[11];
  const float* r1_w      = (const float*)d_in[12];
  const float* r1_b      = (const float*)d_in[13];
  const float* r2_w      = (const float*)d_in[14];
  const float* r2_b      = (const float*)d_in[15];
  const float* r3_w      = (const float*)d_in[16];
  const float* r3_b      = (const float*)d_in[17];
  const float* ssg_w     = (const float*)d_in[18];
  const float* ssg_b     = (const float*)d_in[19];

  char* ws = (char*)d_ws;
  unsigned short* combined = (unsigned short*)(ws);               // 16,777,216
  unsigned short* ssg_in   = (unsigned short*)(ws + 16777216);    //  8,388,608
  unsigned short* W1       = (unsigned short*)(ws + 33554432);    // 25,165,824
  unsigned short* W2       = (unsigned short*)(ws + 58720256);    //  4,194,304
  unsigned short* W3       = (unsigned short*)(ws + 62914560);    //  2,097,152
  unsigned short* W4       = (unsigned short*)(ws + 65011712);    //  2,097,152
  unsigned short* gates    = (unsigned short*)(ws + 67108864);    // 41,943,040
  unsigned short* a_hidden = (unsigned short*)(ws + 109051904);   //  8,388,608
  unsigned short* r1       = (unsigned short*)(ws + 117456896);   //  8,388,608
  unsigned short* r2       = (unsigned short*)(ws + 125845504);   //  8,388,608
  float*          residual = (float*)(ws + 134234112);            // 16,777,216

  float* h_out   = (float*)d_out;
  float* c_out   = h_out + (size_t)B_DIM * H_DIM;
  float* ssg_out = c_out + (size_t)B_DIM * H_DIM;

  prep_kernel<<<4096, 256, 0, stream>>>(x, h_prev, ssg_state, Wx, Ux, a1_w,
                                        ssg_w, r1_w, r2_w, r3_w,
                                        combined, ssg_in, W1, W2, W3, W4);

  gemm8p_mode0<<<(B_DIM / 128) * (N1 / 256), 512, 0, stream>>>(
      combined, W1, bWx, bUx, a1_b, gates, a_hidden);

  gemm_n2048<<<256, 512, 0, stream>>>(
      ssg_in, combined + 1024, W2, ssg_b, r1_b, ssg_out, r1);

  gemm_bf16<2><<<(B_DIM / 128) * (1024 / 128), 256, 0, stream>>>(
      r1, W3, B_DIM, 1024, 1024, r2_b, r2);

  gemm_bf16<3><<<(B_DIM / 128) * (1024 / 128), 256, 0, stream>>>(
      r2, W4, B_DIM, 1024, 1024, r3_b, residual);

  final_fused<<<B_DIM, 256, 0, stream>>>(
      gates, c_prev, a_hidden, a2_w, a2_b, residual, ssg_out, h_out, c_out);
}

// Round 10
// 247.902 us; speedup vs baseline: 1.0884x; 1.0253x over previous
//
#include <hip/hip_runtime.h>
#include <hip/hip_bf16.h>

// Problem constants
#define B_DIM 4096
#define H_DIM 1024
#define K1    2048   // IN + H
#define N1    6144   // 5 gates * 1024 + a1 (1024)

typedef __attribute__((ext_vector_type(8))) short bf16x8;
typedef __attribute__((ext_vector_type(4))) float f32x4;

__device__ __forceinline__ unsigned short f2bf(float f) {
  unsigned int x = __float_as_uint(f);
  x += 0x7fffu + ((x >> 16) & 1u);   // RTNE
  return (unsigned short)(x >> 16);
}
__device__ __forceinline__ float bf2f(unsigned short u) {
  return __uint_as_float(((unsigned int)u) << 16);
}
__device__ __forceinline__ float fast_sigmoid(float x) {
  return __builtin_amdgcn_rcpf(1.0f + __expf(-x));
}
__device__ __forceinline__ float fast_tanh(float x) {
  return 1.0f - 2.0f * __builtin_amdgcn_rcpf(1.0f + __expf(2.0f * x));
}
__device__ __forceinline__ void gload_lds16(const void* g, void* l) {
  __builtin_amdgcn_global_load_lds(
      (const __attribute__((address_space(1))) void*)g,
      (__attribute__((address_space(3))) void*)l, 16, 0, 0);
}

// m201's st_16x32 swizzle: XOR byte-bit5 with bit9 within a 1024B subtile.
__device__ __forceinline__ int swz1k(int x) {
  return x ^ (((x >> 9) & 1) << 5);
}

// ---------------------------------------------------------------------------
// prep: build bf16 activations + weight panels in workspace (grid-stride vec4)
// ---------------------------------------------------------------------------
__global__ __launch_bounds__(256) void prep_kernel(
    const float* __restrict__ x, const float* __restrict__ h,
    const float* __restrict__ ssg_state,
    const float* __restrict__ Wx, const float* __restrict__ Ux,
    const float* __restrict__ a1_w,
    const float* __restrict__ ssg_w, const float* __restrict__ r1_w,
    const float* __restrict__ r2_w, const float* __restrict__ r3_w,
    unsigned short* __restrict__ combined,
    unsigned short* __restrict__ ssg_in,
    unsigned short* __restrict__ W1,
    unsigned short* __restrict__ W2,
    unsigned short* __restrict__ W3,
    unsigned short* __restrict__ W4)
{
  const size_t NV0 = (size_t)B_DIM * K1 / 4;      // combined
  const size_t NV1 = (size_t)B_DIM * H_DIM / 4;   // ssg_in
  const size_t NV3 = (size_t)N1 * K1 / 4;         // W1
  const size_t NV4 = (size_t)2048 * H_DIM / 4;    // W2
  const size_t NV5 = (size_t)H_DIM * H_DIM / 4;   // W3, W4
  const size_t total = NV0 + NV1 + NV3 + NV4 + NV5 + NV5;
  const size_t stride = (size_t)gridDim.x * blockDim.x;

  for (size_t v = (size_t)blockIdx.x * blockDim.x + threadIdx.x; v < total; v += stride) {
    size_t idx = v;
    const float* src;
    unsigned short* dst;
    if (idx < NV0) {
      size_t e = idx * 4, b = e >> 11, k = e & 2047;
      src = (k < 1024) ? &x[(b << 10) + k] : &h[(b << 10) + (k - 1024)];
      dst = &combined[e];
    } else if ((idx -= NV0) < NV1) {
      size_t e = idx * 4;
      float4 a = *(const float4*)&ssg_state[e];
      float4 c = *(const float4*)&h[e];
      ushort4 o;
      o.x = f2bf(a.x + c.x); o.y = f2bf(a.y + c.y);
      o.z = f2bf(a.z + c.z); o.w = f2bf(a.w + c.w);
      *(ushort4*)&ssg_in[e] = o;
      continue;
    } else if ((idx -= NV1) < NV3) {
      size_t e = idx * 4, n = e >> 11, k = e & 2047;
      if (n < 5120) src = (k < 1024) ? &Wx[(n << 10) + k] : &Ux[(n << 10) + (k - 1024)];
      else          src = &a1_w[((n - 5120) << 11) + k];
      dst = &W1[e];
    } else if ((idx -= NV3) < NV4) {
      size_t e = idx * 4, n = e >> 10, k = e & 1023;
      src = (n < 1024) ? &ssg_w[(n << 10) + k] : &r1_w[((n - 1024) << 10) + k];
      dst = &W2[e];
    } else if ((idx -= NV4) < NV5) {
      size_t e = idx * 4; src = &r2_w[e]; dst = &W3[e];
    } else {
      idx -= NV5;
      size_t e = idx * 4; src = &r3_w[e]; dst = &W4[e];
    }
    float4 a = *(const float4*)src;
    ushort4 o;
    o.x = f2bf(a.x); o.y = f2bf(a.y); o.z = f2bf(a.z); o.w = f2bf(a.w);
    *(ushort4*)dst = o;
  }
}

// ---------------------------------------------------------------------------
// gemm_fr<NT, MODE>: 128x128 tile, 256 thr (4 waves 2x2, per-wave 64x64 =
// 4x4 frags, 32 MFMA/K-tile), 1-barrier-per-K-tile (R8 schedule), 64 KB LDS
// -> 2 blocks/CU: inter-block TLP hides the tile-top vmcnt(0)+barrier drain
// (m114 mechanism; m97's 912 TF came from 3 blocks/CU with a worse schedule).
// K = NT*64. Grid = (B/128) * (N/128), full rounds of 512.
// MODE 0: N=6144, A=combined (lda K1): gates (tn<40) + a_hidden (tn>=40)
// MODE 1: N=2048: tn<8 A=ssg_in lda1024 -> ssg_new fp32; tn>=8 A=combined+1024
//         lda2048 -> r1 relu bf16
// ---------------------------------------------------------------------------
template <int NT, int MODE>
__global__ __launch_bounds__(256, 2) void gemm_fr(
    const unsigned short* __restrict__ A0,
    const unsigned short* __restrict__ A1,
    const unsigned short* __restrict__ W,
    const float* __restrict__ b0, const float* __restrict__ b1,
    const float* __restrict__ b2,
    void* __restrict__ out0, void* __restrict__ out1)
{
  __shared__ unsigned short lds[32768];  // 64 KiB: 2 buffers x 16384 shorts

  constexpr int KDIM = NT * 64;
  constexpr int N    = (MODE == 0) ? N1 : 2048;
  constexpr int NTN  = N / 128;
  constexpr int NWG  = (B_DIM / 128) * NTN;

  const int tid  = threadIdx.x;
  const int wave = tid >> 6;
  const int lane = tid & 63;
  const int wm = wave >> 1;      // 0..1 : row half (64)
  const int wn = wave & 1;       // 0..1 : col half (64)

  const int swz = (blockIdx.x & 7) * (NWG / 8) + (blockIdx.x >> 3);
  const int tm = swz / NTN, tn = swz % NTN;
  const int tmB = tm * 128, tnB = tn * 128;

  const unsigned short* Abase = A0;
  int lda = (MODE == 0) ? K1 : 1024;
  if (MODE == 1 && tn >= 8) { Abase = A1; lda = 2048; }

  // ---- stage source addressing (pre-swizzled source, linear dest) ----
  const int sidx = swz1k(lane * 16);
  const int r_l  = sidx >> 6;          // row 0..15 within subtile
  const int kel  = (sidx & 63) >> 1;   // k elem offset (mult of 8)
  // wave covers rows [wave*32, wave*32+32): subtiles wave*2+rg, k-halves j
  const unsigned short* pA[2][2];
  const unsigned short* pB[2][2];
#pragma unroll
  for (int rg = 0; rg < 2; ++rg)
#pragma unroll
    for (int j = 0; j < 2; ++j) {
      const int rr = wave * 32 + rg * 16 + r_l;
      const int kk0 = j * 32 + kel;
      pA[rg][j] = Abase + (size_t)(tmB + rr) * lda + kk0;
      pB[rg][j] = W + (size_t)(tnB + rr) * KDIM + kk0;
    }

  // LDS shorts: buffer p at p*16384; A 8192 (16KB), B at +8192.
#define STAGE_A(tt) do { const int p_ = (tt) & 1;                                \
    _Pragma("unroll")                                                            \
    for (int rg = 0; rg < 2; ++rg)                                               \
      _Pragma("unroll")                                                          \
      for (int j = 0; j < 2; ++j)                                                \
        gload_lds16(pA[rg][j] + (size_t)(tt) * 64,                               \
                    &lds[p_ * 16384 + ((wave * 2 + rg) * 2 + j) * 512]);         \
  } while (0)
#define STAGE_B(tt) do { const int p_ = (tt) & 1;                                \
    _Pragma("unroll")                                                            \
    for (int rg = 0; rg < 2; ++rg)                                               \
      _Pragma("unroll")                                                          \
      for (int j = 0; j < 2; ++j)                                                \
        gload_lds16(pB[rg][j] + (size_t)(tt) * 64,                               \
                    &lds[p_ * 16384 + 8192 + ((wave * 2 + rg) * 2 + j) * 512]);  \
  } while (0)

  // ---- ds_read addressing (R5/R8-verified conflict-free pattern) ----
  const int loc = swz1k((lane & 15) * 64 + (lane >> 4) * 16);

  f32x4 acc[4][4];
#pragma unroll
  for (int m = 0; m < 4; ++m)
#pragma unroll
    for (int n = 0; n < 4; ++n) acc[m][n] = (f32x4){0.f, 0.f, 0.f, 0.f};

  STAGE_A(0); STAGE_B(0);   // 8 vmem ops

#define MFMA16(aV, bV) do {                                                      \
    _Pragma("unroll")                                                            \
    for (int n = 0; n < 4; ++n) {                                                \
      _Pragma("unroll")                                                          \
      for (int m = 0; m < 4; ++m)                                                \
        acc[m][n] = __builtin_amdgcn_mfma_f32_16x16x32_bf16(                     \
            aV[m], bV[n], acc[m][n], 0, 0, 0);                                   \
    } } while (0)

  const char* lchar = (const char*)lds;
  for (int t = 0; t < NT; ++t) {
    asm volatile("s_waitcnt vmcnt(0)" ::: "memory");
    __builtin_amdgcn_s_barrier();

    const char* base = lchar + (t & 1) * 32768;
    const char* bA = base + wm * 8192 + loc;
    const char* bB = base + 16384 + wn * 8192 + loc;

    bf16x8 a0[4], a1[4], b0[4], b1[4];
#pragma unroll
    for (int n = 0; n < 4; ++n) b0[n] = *(const bf16x8*)(bB + (2 * n + 0) * 1024);
#pragma unroll
    for (int m = 0; m < 4; ++m) a0[m] = *(const bf16x8*)(bA + (2 * m + 0) * 1024);
    if (t + 1 < NT) STAGE_A(t + 1);
#pragma unroll
    for (int n = 0; n < 4; ++n) b1[n] = *(const bf16x8*)(bB + (2 * n + 1) * 1024);
#pragma unroll
    for (int m = 0; m < 4; ++m) a1[m] = *(const bf16x8*)(bA + (2 * m + 1) * 1024);
    if (t + 1 < NT) STAGE_B(t + 1);

    __builtin_amdgcn_s_setprio(1);
    MFMA16(a0, b0);
    __builtin_amdgcn_s_setprio(0);
    __builtin_amdgcn_s_setprio(1);
    MFMA16(a1, b1);
    __builtin_amdgcn_s_setprio(0);
  }
#undef MFMA16
#undef STAGE_A
#undef STAGE_B

  const int l15 = lane & 15, lq4 = (lane >> 4) << 2;
  const int rowg0 = tmB + wm * 64;

  if (MODE == 1 && tn < 8) {
    // ssg_new fp32 direct stores
    const int col0 = tn * 128 + wn * 64;
#pragma unroll
    for (int fn = 0; fn < 4; ++fn) {
      const int col = col0 + fn * 16 + l15;
      const float bias = b0[col];
#pragma unroll
      for (int fm = 0; fm < 4; ++fm) {
        f32x4 v = acc[fm][fn];
#pragma unroll
        for (int j = 0; j < 4; ++j) {
          const int r = rowg0 + fm * 16 + lq4 + j;
          ((float*)out0)[(size_t)r * 1024 + col] = v[j] + bias;
        }
      }
    }
    return;
  }

  // bf16 outputs via per-wave slab restage -> coalesced 16B stores
  unsigned short* slab = &lds[wave * 1024];
  const int lr8 = lane >> 3, lc8 = lane & 7;
  bool isgate = false;
  int g = 0, colg0, rowplane = 0;
  unsigned short* outbase;
  if (MODE == 0) {
    isgate = (tn < 40);
    g = tn >> 3;
    colg0 = (isgate ? (tn & 7) : (tn - 40)) * 128 + wn * 64;
    outbase = isgate ? ((unsigned short*)out0 + (size_t)g * ((size_t)B_DIM * 1024))
                     : (unsigned short*)out1;
    (void)rowplane;
  } else {
    colg0 = (tn - 8) * 128 + wn * 64;
    outbase = (unsigned short*)out1;
  }
  float biasv[4];
#pragma unroll
  for (int fn = 0; fn < 4; ++fn) {
    const int c = colg0 + fn * 16 + l15;
    if (MODE == 0) biasv[fn] = isgate ? (b0[g * 1024 + c] + b1[g * 1024 + c]) : b2[c];
    else           biasv[fn] = b1[c];
  }
  __builtin_amdgcn_s_barrier();   // all K-loop LDS traffic fully retired
#pragma unroll
  for (int fm = 0; fm < 4; ++fm) {
#pragma unroll
    for (int fn = 0; fn < 4; ++fn) {
      f32x4 v = acc[fm][fn];
#pragma unroll
      for (int j = 0; j < 4; ++j) {
        const int row = lq4 + j;
        const float xv = v[j] + biasv[fn];
        float res;
        if (MODE == 0 && isgate) res = (g == 3) ? fast_tanh(xv) : fast_sigmoid(xv);
        else                     res = fmaxf(xv, 0.f);
        const int colb = ((fn * 16 + l15) * 2) ^ (((row >> 2) & 3) << 5);
        slab[(row * 128 + colb) >> 1] = f2bf(res);
      }
    }
    asm volatile("s_waitcnt lgkmcnt(0)" ::: "memory");
    __builtin_amdgcn_sched_barrier(0);
#pragma unroll
    for (int rd = 0; rd < 2; ++rd) {
      const int row = rd * 8 + lr8;
      const int cb = (lc8 * 16) ^ (((row >> 2) & 3) << 5);
      bf16x8 pk = *(const bf16x8*)((const char*)slab + row * 128 + cb);
      const size_t r = (size_t)(rowg0 + fm * 16 + row);
      *(bf16x8*)&outbase[r * 1024 + colg0 + lc8 * 8] = pk;
    }
    asm volatile("s_waitcnt lgkmcnt(0)" ::: "memory");
    __builtin_amdgcn_sched_barrier(0);
  }
}

// ---------------------------------------------------------------------------
// m97-style 128x128 GEMM (modes 2, 3: r2 and residual).
// ---------------------------------------------------------------------------
template <int MODE>
__global__ __launch_bounds__(256, 3) void gemm_bf16(
    const unsigned short* __restrict__ A0g,
    const unsigned short* __restrict__ Wg,
    const int M, const int N, const int K,
    const float* __restrict__ b0,
    void* __restrict__ out0)
{
  __shared__ unsigned short As[128 * 64];
  __shared__ unsigned short Bs[128 * 64];

  const int tid  = threadIdx.x;
  const int wave = tid >> 6;
  const int lane = tid & 63;
  const int wm = wave >> 1, wn = wave & 1;

  const int ntn = N >> 7;
  const int tm = blockIdx.x / ntn;
  const int tn = blockIdx.x % ntn;

  const int lrow = lane >> 3;
  const int lk   = (lane & 7) * 8;
  size_t a_off[4], b_off[4];
#pragma unroll
  for (int i = 0; i < 4; ++i) {
    int c = wave * 4 + i;
    int row = c * 8 + lrow;
    a_off[i] = (size_t)(tm * 128 + row) * K + lk;
    b_off[i] = (size_t)(tn * 128 + row) * K + lk;
  }

  f32x4 acc[4][4];
#pragma unroll
  for (int m = 0; m < 4; ++m)
#pragma unroll
    for (int n = 0; n < 4; ++n) acc[m][n] = (f32x4){0.f, 0.f, 0.f, 0.f};

  const int arow  = wm * 64 + (lane & 15);
  const int brow  = wn * 64 + (lane & 15);
  const int kfrag = (lane >> 4) * 8;

  for (int k0 = 0; k0 < K; k0 += 64) {
#pragma unroll
    for (int i = 0; i < 4; ++i) {
      gload_lds16(A0g + a_off[i] + k0, &As[(wave * 4 + i) * 512]);
      gload_lds16(Wg + b_off[i] + k0, &Bs[(wave * 4 + i) * 512]);
    }
    __syncthreads();
#pragma unroll
    for (int kk = 0; kk < 2; ++kk) {
      bf16x8 af[4], bfr[4];
#pragma unroll
      for (int m = 0; m < 4; ++m)
        af[m] = *(const bf16x8*)&As[(arow + m * 16) * 64 + kk * 32 + kfrag];
#pragma unroll
      for (int n = 0; n < 4; ++n)
        bfr[n] = *(const bf16x8*)&Bs[(brow + n * 16) * 64 + kk * 32 + kfrag];
#pragma unroll
      for (int m = 0; m < 4; ++m)
#pragma unroll
        for (int n = 0; n < 4; ++n)
          acc[m][n] = __builtin_amdgcn_mfma_f32_16x16x32_bf16(
              af[m], bfr[n], acc[m][n], 0, 0, 0);
    }
    __syncthreads();
  }

  const int col0 = tn * 128 + wn * 64;
  const int row0 = tm * 128 + wm * 64 + ((lane >> 4) << 2);
#pragma unroll
  for (int n = 0; n < 4; ++n) {
    const int col = col0 + n * 16 + (lane & 15);
    const float bias = b0[col];
#pragma unroll
    for (int m = 0; m < 4; ++m) {
      const int rowb = row0 + m * 16;
      f32x4 v = acc[m][n];
#pragma unroll
      for (int j = 0; j < 4; ++j) {
        const float xv = v[j] + bias;
        const int r = rowb + j;
        if (MODE == 2) {
          ((unsigned short*)out0)[(size_t)r * 1024 + col] = f2bf(fmaxf(xv, 0.f));
        } else {
          ((float*)out0)[(size_t)r * 1024 + col] = xv;               // residual fp32
        }
      }
    }
  }
}

// ---------------------------------------------------------------------------
// final fused: per-row alpha (4-wave reduce) + vec4 elementwise cell update.
// ---------------------------------------------------------------------------
__global__ __launch_bounds__(256) void final_fused(
    const unsigned short* __restrict__ gates,
    const float* __restrict__ c_prev,
    const unsigned short* __restrict__ a_hidden,
    const float* __restrict__ a2_w, const float* __restrict__ a2_b,
    const float* __restrict__ residual,
    const float* __restrict__ ssg_new,
    float* __restrict__ h_out, float* __restrict__ c_out)
{
  __shared__ float red[5];
  const int r = blockIdx.x;
  const int tid = threadIdx.x;
  const size_t BH = (size_t)B_DIM * H_DIM;

  {
    ushort4 u = *(const ushort4*)&a_hidden[(size_t)r * 1024 + tid * 4];
    float4 w = *(const float4*)&a2_w[tid * 4];
    float s = bf2f(u.x) * w.x + bf2f(u.y) * w.y + bf2f(u.z) * w.z + bf2f(u.w) * w.w;
#pragma unroll
    for (int off = 32; off; off >>= 1) s += __shfl_xor(s, off);
    if ((tid & 63) == 0) red[tid >> 6] = s;
  }
  __syncthreads();
  if (tid == 0)
    red[4] = fast_sigmoid(red[0] + red[1] + red[2] + red[3] + a2_b[0]);
  __syncthreads();
  const float al = red[4];

  const size_t e = (size_t)r * 1024 + tid * 4;
  ushort4 iu = *(const ushort4*)&gates[e];
  ushort4 fu = *(const ushort4*)&gates[BH + e];
  ushort4 ou = *(const ushort4*)&gates[2 * BH + e];
  ushort4 cu = *(const ushort4*)&gates[3 * BH + e];
  ushort4 su = *(const ushort4*)&gates[4 * BH + e];
  float4 cp = *(const float4*)&c_prev[e];
  float4 rs = *(const float4*)&residual[e];
  float4 sg = *(const float4*)&ssg_new[e];
  float4 ho, co;
  co.x = bf2f(fu.x) * cp.x + bf2f(iu.x) * bf2f(cu.x) * bf2f(su.x) * al * sg.x + rs.x;
  co.y = bf2f(fu.y) * cp.y + bf2f(iu.y) * bf2f(cu.y) * bf2f(su.y) * al * sg.y + rs.y;
  co.z = bf2f(fu.z) * cp.z + bf2f(iu.z) * bf2f(cu.z) * bf2f(su.z) * al * sg.z + rs.z;
  co.w = bf2f(fu.w) * cp.w + bf2f(iu.w) * bf2f(cu.w) * bf2f(su.w) * al * sg.w + rs.w;
  ho.x = bf2f(ou.x) * fast_tanh(co.x);
  ho.y = bf2f(ou.y) * fast_tanh(co.y);
  ho.z = bf2f(ou.z) * fast_tanh(co.z);
  ho.w = bf2f(ou.w) * fast_tanh(co.w);
  *(float4*)&h_out[e] = ho;
  *(float4*)&c_out[e] = co;
}

// ---------------------------------------------------------------------------
extern "C" void kernel_launch(void* const* d_in, const int* in_sizes, int n_in,
                              void* d_out, int out_size, void* d_ws, size_t ws_size,
                              hipStream_t stream)
{
  (void)in_sizes; (void)n_in; (void)out_size; (void)ws_size;
  const float* x         = (const float*)d_in[0];
  const float* h_prev    = (const float*)d_in[1];
  const float* c_prev    = (const float*)d_in[2];
  const float* ssg_state = (const float*)d_in[3];
  const float* Wx        = (const float*)d_in[4];
  const float* bWx       = (const float*)d_in[5];
  const float* Ux        = (const float*)d_in[6];
  const float* bUx       = (const float*)d_in[7];
  const float* a1_w      = (const float*)d_in[8];
  const float* a1_b      = (const float*)d_in[9];
  const float* a2_w      = (const float*)d_in[10];
  const float* a2_b      = (const float*)d_in[11];
  const float* r1_w      = (const float*)d_in[12];
  const float* r1_b      = (const float*)d_in[13];
  const float* r2_w      = (const float*)d_in[14];
  const float* r2_b      = (const float*)d_in[15];
  const float* r3_w      = (const float*)d_in[16];
  const float* r3_b      = (const float*)d_in[17];
  const float* ssg_w     = (const float*)d_in[18];
  const float* ssg_b     = (const float*)d_in[19];

  char* ws = (char*)d_ws;
  unsigned short* combined = (unsigned short*)(ws);               // 16,777,216
  unsigned short* ssg_in   = (unsigned short*)(ws + 16777216);    //  8,388,608
  unsigned short* W1       = (unsigned short*)(ws + 33554432);    // 25,165,824
  unsigned short* W2       = (unsigned short*)(ws + 58720256);    //  4,194,304
  unsigned short* W3       = (unsigned short*)(ws + 62914560);    //  2,097,152
  unsigned short* W4       = (unsigned short*)(ws + 65011712);    //  2,097,152
  unsigned short* gates    = (unsigned short*)(ws + 67108864);    // 41,943,040
  unsigned short* a_hidden = (unsigned short*)(ws + 109051904);   //  8,388,608
  unsigned short* r1       = (unsigned short*)(ws + 117456896);   //  8,388,608
  unsigned short* r2       = (unsigned short*)(ws + 125845504);   //  8,388,608
  float*          residual = (float*)(ws + 134234112);            // 16,777,216

  float* h_out   = (float*)d_out;
  float* c_out   = h_out + (size_t)B_DIM * H_DIM;
  float* ssg_out = c_out + (size_t)B_DIM * H_DIM;

  prep_kernel<<<4096, 256, 0, stream>>>(x, h_prev, ssg_state, Wx, Ux, a1_w,
                                        ssg_w, r1_w, r2_w, r3_w,
                                        combined, ssg_in, W1, W2, W3, W4);

  gemm_fr<32, 0><<<(B_DIM / 128) * (N1 / 128), 256, 0, stream>>>(
      combined, nullptr, W1, bWx, bUx, a1_b, gates, a_hidden);

  gemm_fr<16, 1><<<(B_DIM / 128) * (2048 / 128), 256, 0, stream>>>(
      ssg_in, combined + 1024, W2, ssg_b, r1_b, nullptr, ssg_out, r1);

  gemm_bf16<2><<<(B_DIM / 128) * (1024 / 128), 256, 0, stream>>>(
      r1, W3, B_DIM, 1024, 1024, r2_b, r2);

  gemm_bf16<3><<<(B_DIM / 128) * (1024 / 128), 256, 0, stream>>>(
      r2, W4, B_DIM, 1024, 1024, r3_b, residual);

  final_fused<<<B_DIM, 256, 0, stream>>>(
      gates, c_prev, a_hidden, a2_w, a2_b, residual, ssg_out, h_out, c_out);
}

// Round 11
// 223.986 us; speedup vs baseline: 1.2046x; 1.1068x over previous
//
#include <hip/hip_runtime.h>
#include <hip/hip_bf16.h>

// Problem constants
#define B_DIM 4096
#define H_DIM 1024
#define K1    2048   // IN + H
#define N1    6144   // 5 gates * 1024 + a1 (1024)

typedef __attribute__((ext_vector_type(8))) short bf16x8;
typedef __attribute__((ext_vector_type(4))) float f32x4;

__device__ __forceinline__ unsigned short f2bf(float f) {
  unsigned int x = __float_as_uint(f);
  x += 0x7fffu + ((x >> 16) & 1u);   // RTNE
  return (unsigned short)(x >> 16);
}
__device__ __forceinline__ float bf2f(unsigned short u) {
  return __uint_as_float(((unsigned int)u) << 16);
}
__device__ __forceinline__ float fast_sigmoid(float x) {
  return __builtin_amdgcn_rcpf(1.0f + __expf(-x));
}
__device__ __forceinline__ float fast_tanh(float x) {
  return 1.0f - 2.0f * __builtin_amdgcn_rcpf(1.0f + __expf(2.0f * x));
}
__device__ __forceinline__ void gload_lds16(const void* g, void* l) {
  __builtin_amdgcn_global_load_lds(
      (const __attribute__((address_space(1))) void*)g,
      (__attribute__((address_space(3))) void*)l, 16, 0, 0);
}

// m201's st_16x32 swizzle: XOR byte-bit5 with bit9 within a 1024B subtile.
__device__ __forceinline__ int swz1k(int x) {
  return x ^ (((x >> 9) & 1) << 5);
}

// ---------------------------------------------------------------------------
// prep: build bf16 activations + weight panels in workspace (grid-stride vec4)
// ---------------------------------------------------------------------------
__global__ __launch_bounds__(256) void prep_kernel(
    const float* __restrict__ x, const float* __restrict__ h,
    const float* __restrict__ ssg_state,
    const float* __restrict__ Wx, const float* __restrict__ Ux,
    const float* __restrict__ a1_w,
    const float* __restrict__ ssg_w, const float* __restrict__ r1_w,
    const float* __restrict__ r2_w, const float* __restrict__ r3_w,
    unsigned short* __restrict__ combined,
    unsigned short* __restrict__ ssg_in,
    unsigned short* __restrict__ W1,
    unsigned short* __restrict__ W2,
    unsigned short* __restrict__ W3,
    unsigned short* __restrict__ W4)
{
  const size_t NV0 = (size_t)B_DIM * K1 / 4;      // combined
  const size_t NV1 = (size_t)B_DIM * H_DIM / 4;   // ssg_in
  const size_t NV3 = (size_t)N1 * K1 / 4;         // W1
  const size_t NV4 = (size_t)2048 * H_DIM / 4;    // W2
  const size_t NV5 = (size_t)H_DIM * H_DIM / 4;   // W3, W4
  const size_t total = NV0 + NV1 + NV3 + NV4 + NV5 + NV5;
  const size_t stride = (size_t)gridDim.x * blockDim.x;

  for (size_t v = (size_t)blockIdx.x * blockDim.x + threadIdx.x; v < total; v += stride) {
    size_t idx = v;
    const float* src;
    unsigned short* dst;
    if (idx < NV0) {
      size_t e = idx * 4, b = e >> 11, k = e & 2047;
      src = (k < 1024) ? &x[(b << 10) + k] : &h[(b << 10) + (k - 1024)];
      dst = &combined[e];
    } else if ((idx -= NV0) < NV1) {
      size_t e = idx * 4;
      float4 a = *(const float4*)&ssg_state[e];
      float4 c = *(const float4*)&h[e];
      ushort4 o;
      o.x = f2bf(a.x + c.x); o.y = f2bf(a.y + c.y);
      o.z = f2bf(a.z + c.z); o.w = f2bf(a.w + c.w);
      *(ushort4*)&ssg_in[e] = o;
      continue;
    } else if ((idx -= NV1) < NV3) {
      size_t e = idx * 4, n = e >> 11, k = e & 2047;
      if (n < 5120) src = (k < 1024) ? &Wx[(n << 10) + k] : &Ux[(n << 10) + (k - 1024)];
      else          src = &a1_w[((n - 5120) << 11) + k];
      dst = &W1[e];
    } else if ((idx -= NV3) < NV4) {
      size_t e = idx * 4, n = e >> 10, k = e & 1023;
      src = (n < 1024) ? &ssg_w[(n << 10) + k] : &r1_w[((n - 1024) << 10) + k];
      dst = &W2[e];
    } else if ((idx -= NV4) < NV5) {
      size_t e = idx * 4; src = &r2_w[e]; dst = &W3[e];
    } else {
      idx -= NV5;
      size_t e = idx * 4; src = &r3_w[e]; dst = &W4[e];
    }
    float4 a = *(const float4*)src;
    ushort4 o;
    o.x = f2bf(a.x); o.y = f2bf(a.y); o.z = f2bf(a.z); o.w = f2bf(a.w);
    *(ushort4*)dst = o;
  }
}

// ---------------------------------------------------------------------------
// gemm_body<NT, MODE>: 128x128 tile, 256 thr (4 waves 2x2, per-wave 64x64),
// 1-barrier-per-K-tile (R8-verified schedule), 64 KB LDS (2 blocks/CU).
// K = NT*64; grid = 32 * NTN.
// MODE 0: N=6144, A=combined lda K1: gates (tn<40) + a_hidden (tn>=40)
// MODE 1: N=2048: tn<8 A=A0 lda1024 -> fp32 out0; tn>=8 A=A1 lda2048 ->
//         relu bf16 out1
// MODE 2: N=1024, A=A0 lda1024 -> relu bf16 out1
// MODE 3: N=1024, A=A0 lda1024 -> fp32 out0 (+bias b0)
// ---------------------------------------------------------------------------
template <int NT, int MODE>
__device__ __forceinline__ void gemm_body(
    unsigned short* lds, const int bid,
    const unsigned short* __restrict__ A0,
    const unsigned short* __restrict__ A1,
    const unsigned short* __restrict__ W,
    const float* __restrict__ b0, const float* __restrict__ b1,
    const float* __restrict__ b2,
    void* __restrict__ out0, void* __restrict__ out1)
{
  constexpr int KDIM = NT * 64;
  constexpr int NTN  = (MODE == 0) ? 48 : (MODE == 1 ? 16 : 8);
  constexpr int NWG  = 32 * NTN;

  const int tid  = threadIdx.x;
  const int wave = tid >> 6;
  const int lane = tid & 63;
  const int wm = wave >> 1;
  const int wn = wave & 1;

  const int swz = (bid & 7) * (NWG / 8) + (bid >> 3);
  const int tm = swz / NTN, tn = swz % NTN;
  const int tmB = tm * 128, tnB = tn * 128;

  const unsigned short* Abase = A0;
  int lda = (MODE == 0) ? K1 : 1024;
  if (MODE == 1 && tn >= 8) { Abase = A1; lda = 2048; }

  // ---- stage source addressing (pre-swizzled source, linear dest) ----
  const int sidx = swz1k(lane * 16);
  const int r_l  = sidx >> 6;
  const int kel  = (sidx & 63) >> 1;
  const unsigned short* pA[2][2];
  const unsigned short* pB[2][2];
#pragma unroll
  for (int rg = 0; rg < 2; ++rg)
#pragma unroll
    for (int j = 0; j < 2; ++j) {
      const int rr = wave * 32 + rg * 16 + r_l;
      const int kk0 = j * 32 + kel;
      pA[rg][j] = Abase + (size_t)(tmB + rr) * lda + kk0;
      pB[rg][j] = W + (size_t)(tnB + rr) * KDIM + kk0;
    }

#define STAGE_A(tt) do { const int p_ = (tt) & 1;                                \
    _Pragma("unroll")                                                            \
    for (int rg = 0; rg < 2; ++rg)                                               \
      _Pragma("unroll")                                                          \
      for (int j = 0; j < 2; ++j)                                                \
        gload_lds16(pA[rg][j] + (size_t)(tt) * 64,                               \
                    &lds[p_ * 16384 + ((wave * 2 + rg) * 2 + j) * 512]);         \
  } while (0)
#define STAGE_B(tt) do { const int p_ = (tt) & 1;                                \
    _Pragma("unroll")                                                            \
    for (int rg = 0; rg < 2; ++rg)                                               \
      _Pragma("unroll")                                                          \
      for (int j = 0; j < 2; ++j)                                                \
        gload_lds16(pB[rg][j] + (size_t)(tt) * 64,                               \
                    &lds[p_ * 16384 + 8192 + ((wave * 2 + rg) * 2 + j) * 512]);  \
  } while (0)

  const int loc = swz1k((lane & 15) * 64 + (lane >> 4) * 16);

  f32x4 acc[4][4];
#pragma unroll
  for (int m = 0; m < 4; ++m)
#pragma unroll
    for (int n = 0; n < 4; ++n) acc[m][n] = (f32x4){0.f, 0.f, 0.f, 0.f};

  STAGE_A(0); STAGE_B(0);

#define MFMA16(aV, bV) do {                                                      \
    _Pragma("unroll")                                                            \
    for (int n = 0; n < 4; ++n) {                                                \
      _Pragma("unroll")                                                          \
      for (int m = 0; m < 4; ++m)                                                \
        acc[m][n] = __builtin_amdgcn_mfma_f32_16x16x32_bf16(                     \
            aV[m], bV[n], acc[m][n], 0, 0, 0);                                   \
    } } while (0)

  const char* lchar = (const char*)lds;
  for (int t = 0; t < NT; ++t) {
    asm volatile("s_waitcnt vmcnt(0)" ::: "memory");
    __builtin_amdgcn_s_barrier();

    const char* base = lchar + (t & 1) * 32768;
    const char* bA = base + wm * 8192 + loc;
    const char* bB = base + 16384 + wn * 8192 + loc;

    bf16x8 a0[4], a1[4], b0v[4], b1v[4];
#pragma unroll
    for (int n = 0; n < 4; ++n) b0v[n] = *(const bf16x8*)(bB + (2 * n + 0) * 1024);
#pragma unroll
    for (int m = 0; m < 4; ++m) a0[m] = *(const bf16x8*)(bA + (2 * m + 0) * 1024);
    if (t + 1 < NT) STAGE_A(t + 1);
#pragma unroll
    for (int n = 0; n < 4; ++n) b1v[n] = *(const bf16x8*)(bB + (2 * n + 1) * 1024);
#pragma unroll
    for (int m = 0; m < 4; ++m) a1[m] = *(const bf16x8*)(bA + (2 * m + 1) * 1024);
    if (t + 1 < NT) STAGE_B(t + 1);

    __builtin_amdgcn_s_setprio(1);
    MFMA16(a0, b0v);
    __builtin_amdgcn_s_setprio(0);
    __builtin_amdgcn_s_setprio(1);
    MFMA16(a1, b1v);
    __builtin_amdgcn_s_setprio(0);
  }
#undef MFMA16
#undef STAGE_A
#undef STAGE_B

  const int l15 = lane & 15, lq4 = (lane >> 4) << 2;
  const int rowg0 = tmB + wm * 64;

  if ((MODE == 1 && tn < 8) || MODE == 3) {
    // fp32 direct stores (ssg_new / residual)
    const int col0 = tn * 128 + wn * 64;
#pragma unroll
    for (int fn = 0; fn < 4; ++fn) {
      const int col = col0 + fn * 16 + l15;
      const float bias = b0[col];
#pragma unroll
      for (int fm = 0; fm < 4; ++fm) {
        f32x4 v = acc[fm][fn];
#pragma unroll
        for (int j = 0; j < 4; ++j) {
          const int r = rowg0 + fm * 16 + lq4 + j;
          ((float*)out0)[(size_t)r * 1024 + col] = v[j] + bias;
        }
      }
    }
    return;
  }

  // bf16 outputs via per-wave slab restage -> coalesced 16B stores
  unsigned short* slab = &lds[wave * 1024];
  const int lr8 = lane >> 3, lc8 = lane & 7;
  bool isgate = false;
  int g = 0, colg0;
  unsigned short* outbase;
  if (MODE == 0) {
    isgate = (tn < 40);
    g = tn >> 3;
    colg0 = (isgate ? (tn & 7) : (tn - 40)) * 128 + wn * 64;
    outbase = isgate ? ((unsigned short*)out0 + (size_t)g * ((size_t)B_DIM * 1024))
                     : (unsigned short*)out1;
  } else if (MODE == 1) {
    colg0 = (tn - 8) * 128 + wn * 64;
    outbase = (unsigned short*)out1;
  } else {  // MODE 2
    colg0 = tn * 128 + wn * 64;
    outbase = (unsigned short*)out1;
  }
  float biasv[4];
#pragma unroll
  for (int fn = 0; fn < 4; ++fn) {
    const int c = colg0 + fn * 16 + l15;
    if (MODE == 0) biasv[fn] = isgate ? (b0[g * 1024 + c] + b1[g * 1024 + c]) : b2[c];
    else           biasv[fn] = b1[c];
  }
  __builtin_amdgcn_s_barrier();
#pragma unroll
  for (int fm = 0; fm < 4; ++fm) {
#pragma unroll
    for (int fn = 0; fn < 4; ++fn) {
      f32x4 v = acc[fm][fn];
#pragma unroll
      for (int j = 0; j < 4; ++j) {
        const int row = lq4 + j;
        const float xv = v[j] + biasv[fn];
        float res;
        if (MODE == 0 && isgate) res = (g == 3) ? fast_tanh(xv) : fast_sigmoid(xv);
        else                     res = fmaxf(xv, 0.f);
        const int colb = ((fn * 16 + l15) * 2) ^ (((row >> 2) & 3) << 5);
        slab[(row * 128 + colb) >> 1] = f2bf(res);
      }
    }
    asm volatile("s_waitcnt lgkmcnt(0)" ::: "memory");
    __builtin_amdgcn_sched_barrier(0);
#pragma unroll
    for (int rd = 0; rd < 2; ++rd) {
      const int row = rd * 8 + lr8;
      const int cb = (lc8 * 16) ^ (((row >> 2) & 3) << 5);
      bf16x8 pk = *(const bf16x8*)((const char*)slab + row * 128 + cb);
      const size_t r = (size_t)(rowg0 + fm * 16 + row);
      *(bf16x8*)&outbase[r * 1024 + colg0 + lc8 * 8] = pk;
    }
    asm volatile("s_waitcnt lgkmcnt(0)" ::: "memory");
    __builtin_amdgcn_sched_barrier(0);
  }
}

// ---------------------------------------------------------------------------
// merged big GEMM: blocks [0,1536) = gates+a_hidden; [1536,2048) = ssg+r1.
// Segments are independent; merge removes a launch boundary and lets the
// short segment backfill CUs during the long segment's final partial round.
// ---------------------------------------------------------------------------
__global__ __launch_bounds__(256, 2) void gemm_big(
    const unsigned short* __restrict__ combined,
    const unsigned short* __restrict__ ssg_in,
    const unsigned short* __restrict__ W1,
    const unsigned short* __restrict__ W2,
    const float* __restrict__ bWx, const float* __restrict__ bUx,
    const float* __restrict__ a1_b,
    const float* __restrict__ ssg_b, const float* __restrict__ r1_b,
    unsigned short* __restrict__ gates,
    unsigned short* __restrict__ a_hidden,
    float* __restrict__ ssg_out,
    unsigned short* __restrict__ r1)
{
  __shared__ unsigned short lds[32768];
  const int bid = blockIdx.x;
  if (bid < 1536) {
    gemm_body<32, 0>(lds, bid, combined, nullptr, W1,
                     bWx, bUx, a1_b, gates, a_hidden);
  } else {
    gemm_body<16, 1>(lds, bid - 1536, ssg_in, combined + 1024, W2,
                     ssg_b, r1_b, nullptr, ssg_out, r1);
  }
}

// r2 / residual GEMMs on the same structure
template <int MODE>
__global__ __launch_bounds__(256, 2) void gemm_small(
    const unsigned short* __restrict__ A,
    const unsigned short* __restrict__ W,
    const float* __restrict__ bias,
    void* __restrict__ out)
{
  __shared__ unsigned short lds[32768];
  if (MODE == 2) gemm_body<16, 2>(lds, blockIdx.x, A, nullptr, W,
                                  nullptr, bias, nullptr, nullptr, out);
  else           gemm_body<16, 3>(lds, blockIdx.x, A, nullptr, W,
                                  bias, nullptr, nullptr, out, nullptr);
}

// ---------------------------------------------------------------------------
// final fused: per-row alpha (4-wave reduce) + vec4 elementwise cell update.
// ---------------------------------------------------------------------------
__global__ __launch_bounds__(256) void final_fused(
    const unsigned short* __restrict__ gates,
    const float* __restrict__ c_prev,
    const unsigned short* __restrict__ a_hidden,
    const float* __restrict__ a2_w, const float* __restrict__ a2_b,
    const float* __restrict__ residual,
    const float* __restrict__ ssg_new,
    float* __restrict__ h_out, float* __restrict__ c_out)
{
  __shared__ float red[5];
  const int r = blockIdx.x;
  const int tid = threadIdx.x;
  const size_t BH = (size_t)B_DIM * H_DIM;

  {
    ushort4 u = *(const ushort4*)&a_hidden[(size_t)r * 1024 + tid * 4];
    float4 w = *(const float4*)&a2_w[tid * 4];
    float s = bf2f(u.x) * w.x + bf2f(u.y) * w.y + bf2f(u.z) * w.z + bf2f(u.w) * w.w;
#pragma unroll
    for (int off = 32; off; off >>= 1) s += __shfl_xor(s, off);
    if ((tid & 63) == 0) red[tid >> 6] = s;
  }
  __syncthreads();
  if (tid == 0)
    red[4] = fast_sigmoid(red[0] + red[1] + red[2] + red[3] + a2_b[0]);
  __syncthreads();
  const float al = red[4];

  const size_t e = (size_t)r * 1024 + tid * 4;
  ushort4 iu = *(const ushort4*)&gates[e];
  ushort4 fu = *(const ushort4*)&gates[BH + e];
  ushort4 ou = *(const ushort4*)&gates[2 * BH + e];
  ushort4 cu = *(const ushort4*)&gates[3 * BH + e];
  ushort4 su = *(const ushort4*)&gates[4 * BH + e];
  float4 cp = *(const float4*)&c_prev[e];
  float4 rs = *(const float4*)&residual[e];
  float4 sg = *(const float4*)&ssg_new[e];
  float4 ho, co;
  co.x = bf2f(fu.x) * cp.x + bf2f(iu.x) * bf2f(cu.x) * bf2f(su.x) * al * sg.x + rs.x;
  co.y = bf2f(fu.y) * cp.y + bf2f(iu.y) * bf2f(cu.y) * bf2f(su.y) * al * sg.y + rs.y;
  co.z = bf2f(fu.z) * cp.z + bf2f(iu.z) * bf2f(cu.z) * bf2f(su.z) * al * sg.z + rs.z;
  co.w = bf2f(fu.w) * cp.w + bf2f(iu.w) * bf2f(cu.w) * bf2f(su.w) * al * sg.w + rs.w;
  ho.x = bf2f(ou.x) * fast_tanh(co.x);
  ho.y = bf2f(ou.y) * fast_tanh(co.y);
  ho.z = bf2f(ou.z) * fast_tanh(co.z);
  ho.w = bf2f(ou.w) * fast_tanh(co.w);
  *(float4*)&h_out[e] = ho;
  *(float4*)&c_out[e] = co;
}

// ---------------------------------------------------------------------------
extern "C" void kernel_launch(void* const* d_in, const int* in_sizes, int n_in,
                              void* d_out, int out_size, void* d_ws, size_t ws_size,
                              hipStream_t stream)
{
  (void)in_sizes; (void)n_in; (void)out_size; (void)ws_size;
  const float* x         = (const float*)d_in[0];
  const float* h_prev    = (const float*)d_in[1];
  const float* c_prev    = (const float*)d_in[2];
  const float* ssg_state = (const float*)d_in[3];
  const float* Wx        = (const float*)d_in[4];
  const float* bWx       = (const float*)d_in[5];
  const float* Ux        = (const float*)d_in[6];
  const float* bUx       = (const float*)d_in[7];
  const float* a1_w      = (const float*)d_in[8];
  const float* a1_b      = (const float*)d_in[9];
  const float* a2_w      = (const float*)d_in[10];
  const float* a2_b      = (const float*)d_in[11];
  const float* r1_w      = (const float*)d_in[12];
  const float* r1_b      = (const float*)d_in[13];
  const float* r2_w      = (const float*)d_in[14];
  const float* r2_b      = (const float*)d_in[15];
  const float* r3_w      = (const float*)d_in[16];
  const float* r3_b      = (const float*)d_in[17];
  const float* ssg_w     = (const float*)d_in[18];
  const float* ssg_b     = (const float*)d_in[19];

  char* ws = (char*)d_ws;
  unsigned short* combined = (unsigned short*)(ws);               // 16,777,216
  unsigned short* ssg_in   = (unsigned short*)(ws + 16777216);    //  8,388,608
  unsigned short* W1       = (unsigned short*)(ws + 33554432);    // 25,165,824
  unsigned short* W2       = (unsigned short*)(ws + 58720256);    //  4,194,304
  unsigned short* W3       = (unsigned short*)(ws + 62914560);    //  2,097,152
  unsigned short* W4       = (unsigned short*)(ws + 65011712);    //  2,097,152
  unsigned short* gates    = (unsigned short*)(ws + 67108864);    // 41,943,040
  unsigned short* a_hidden = (unsigned short*)(ws + 109051904);   //  8,388,608
  unsigned short* r1       = (unsigned short*)(ws + 117456896);   //  8,388,608
  unsigned short* r2       = (unsigned short*)(ws + 125845504);   //  8,388,608
  float*          residual = (float*)(ws + 134234112);            // 16,777,216

  float* h_out   = (float*)d_out;
  float* c_out   = h_out + (size_t)B_DIM * H_DIM;
  float* ssg_out = c_out + (size_t)B_DIM * H_DIM;

  prep_kernel<<<4096, 256, 0, stream>>>(x, h_prev, ssg_state, Wx, Ux, a1_w,
                                        ssg_w, r1_w, r2_w, r3_w,
                                        combined, ssg_in, W1, W2, W3, W4);

  gemm_big<<<2048, 256, 0, stream>>>(
      combined, ssg_in, W1, W2, bWx, bUx, a1_b, ssg_b, r1_b,
      gates, a_hidden, ssg_out, r1);

  gemm_small<2><<<256, 256, 0, stream>>>(r1, W3, r2_b, r2);

  gemm_small<3><<<256, 256, 0, stream>>>(r2, W4, r3_b, residual);

  final_fused<<<B_DIM, 256, 0, stream>>>(
      gates, c_prev, a_hidden, a2_w, a2_b, residual, ssg_out, h_out, c_out);
}

// Round 12
// 219.658 us; speedup vs baseline: 1.2284x; 1.0197x over previous
//
#include <hip/hip_runtime.h>
#include <hip/hip_bf16.h>

// Problem constants
#define B_DIM 4096
#define H_DIM 1024
#define K1    2048   // IN + H
#define N1    6144   // 5 gates * 1024 + a1 (1024)

typedef __attribute__((ext_vector_type(8))) short bf16x8;
typedef __attribute__((ext_vector_type(4))) float f32x4;

__device__ __forceinline__ unsigned short f2bf(float f) {
  unsigned int x = __float_as_uint(f);
  x += 0x7fffu + ((x >> 16) & 1u);   // RTNE
  return (unsigned short)(x >> 16);
}
__device__ __forceinline__ float bf2f(unsigned short u) {
  return __uint_as_float(((unsigned int)u) << 16);
}
__device__ __forceinline__ float fast_sigmoid(float x) {
  return __builtin_amdgcn_rcpf(1.0f + __expf(-x));
}
__device__ __forceinline__ float fast_tanh(float x) {
  return 1.0f - 2.0f * __builtin_amdgcn_rcpf(1.0f + __expf(2.0f * x));
}
__device__ __forceinline__ void gload_lds16(const void* g, void* l) {
  __builtin_amdgcn_global_load_lds(
      (const __attribute__((address_space(1))) void*)g,
      (__attribute__((address_space(3))) void*)l, 16, 0, 0);
}

// m201's st_16x32 swizzle: XOR byte-bit5 with bit9 within a 1024B subtile.
__device__ __forceinline__ int swz1k(int x) {
  return x ^ (((x >> 9) & 1) << 5);
}

// ---------------------------------------------------------------------------
// prep: build bf16 activations + weight panels in workspace (grid-stride vec4)
// ---------------------------------------------------------------------------
__global__ __launch_bounds__(256) void prep_kernel(
    const float* __restrict__ x, const float* __restrict__ h,
    const float* __restrict__ ssg_state,
    const float* __restrict__ Wx, const float* __restrict__ Ux,
    const float* __restrict__ a1_w,
    const float* __restrict__ ssg_w, const float* __restrict__ r1_w,
    const float* __restrict__ r2_w, const float* __restrict__ r3_w,
    unsigned short* __restrict__ combined,
    unsigned short* __restrict__ ssg_in,
    unsigned short* __restrict__ W1,
    unsigned short* __restrict__ W2,
    unsigned short* __restrict__ W3,
    unsigned short* __restrict__ W4)
{
  const size_t NV0 = (size_t)B_DIM * K1 / 4;      // combined
  const size_t NV1 = (size_t)B_DIM * H_DIM / 4;   // ssg_in
  const size_t NV3 = (size_t)N1 * K1 / 4;         // W1
  const size_t NV4 = (size_t)2048 * H_DIM / 4;    // W2
  const size_t NV5 = (size_t)H_DIM * H_DIM / 4;   // W3, W4
  const size_t total = NV0 + NV1 + NV3 + NV4 + NV5 + NV5;
  const size_t stride = (size_t)gridDim.x * blockDim.x;

  for (size_t v = (size_t)blockIdx.x * blockDim.x + threadIdx.x; v < total; v += stride) {
    size_t idx = v;
    const float* src;
    unsigned short* dst;
    if (idx < NV0) {
      size_t e = idx * 4, b = e >> 11, k = e & 2047;
      src = (k < 1024) ? &x[(b << 10) + k] : &h[(b << 10) + (k - 1024)];
      dst = &combined[e];
    } else if ((idx -= NV0) < NV1) {
      size_t e = idx * 4;
      float4 a = *(const float4*)&ssg_state[e];
      float4 c = *(const float4*)&h[e];
      ushort4 o;
      o.x = f2bf(a.x + c.x); o.y = f2bf(a.y + c.y);
      o.z = f2bf(a.z + c.z); o.w = f2bf(a.w + c.w);
      *(ushort4*)&ssg_in[e] = o;
      continue;
    } else if ((idx -= NV1) < NV3) {
      size_t e = idx * 4, n = e >> 11, k = e & 2047;
      if (n < 5120) src = (k < 1024) ? &Wx[(n << 10) + k] : &Ux[(n << 10) + (k - 1024)];
      else          src = &a1_w[((n - 5120) << 11) + k];
      dst = &W1[e];
    } else if ((idx -= NV3) < NV4) {
      size_t e = idx * 4, n = e >> 10, k = e & 1023;
      src = (n < 1024) ? &ssg_w[(n << 10) + k] : &r1_w[((n - 1024) << 10) + k];
      dst = &W2[e];
    } else if ((idx -= NV4) < NV5) {
      size_t e = idx * 4; src = &r2_w[e]; dst = &W3[e];
    } else {
      idx -= NV5;
      size_t e = idx * 4; src = &r3_w[e]; dst = &W4[e];
    }
    float4 a = *(const float4*)src;
    ushort4 o;
    o.x = f2bf(a.x); o.y = f2bf(a.y); o.z = f2bf(a.z); o.w = f2bf(a.w);
    *(ushort4*)dst = o;
  }
}

// ---------------------------------------------------------------------------
// body192: 128x192 tile, 256 thr (4 waves 2x2, per-wave 64x96 = 4x6 frags,
// 48 MFMA/K-tile), 1-barrier-per-K-tile (R8-verified schedule), 80 KB LDS
// (2 blocks/CU). LDS-traffic ratio 0.417 KB/MFMA vs 0.5 at 4x4 (this round's
// experiment: is gemm1 LDS-read-BW bound?). N=6144 only (MODE-0 epilogue).
// ---------------------------------------------------------------------------
__device__ __forceinline__ void body192(
    unsigned short* lds, const int bid,
    const unsigned short* __restrict__ A,
    const unsigned short* __restrict__ W,
    const float* __restrict__ bWx, const float* __restrict__ bUx,
    const float* __restrict__ a1_b,
    unsigned short* __restrict__ gates,
    unsigned short* __restrict__ a_hidden)
{
  constexpr int NT  = 32;       // K = 2048
  constexpr int NTN = 32;       // 6144 / 192
  constexpr int NWG = 32 * NTN; // 1024

  const int tid  = threadIdx.x;
  const int wave = tid >> 6;
  const int lane = tid & 63;
  const int wm = wave >> 1;     // row half (64)
  const int wn = wave & 1;      // col half (96)

  const int swz = (bid & 7) * (NWG / 8) + (bid >> 3);
  const int tm = swz / NTN, tn = swz % NTN;
  const int tmB = tm * 128, tnB = tn * 192;

  // ---- stage source addressing (pre-swizzled source, linear dest) ----
  const int sidx = swz1k(lane * 16);
  const int r_l  = sidx >> 6;
  const int kel  = (sidx & 63) >> 1;
  // A: 8 row-subtiles (rg), wave stages rg = 2w..2w+1; B: 12, rg = 3w..3w+2
  const unsigned short* pA[2][2];
  const unsigned short* pB[3][2];
#pragma unroll
  for (int rg = 0; rg < 2; ++rg)
#pragma unroll
    for (int j = 0; j < 2; ++j)
      pA[rg][j] = A + (size_t)(tmB + (wave * 2 + rg) * 16 + r_l) * K1 + j * 32 + kel;
#pragma unroll
  for (int rg = 0; rg < 3; ++rg)
#pragma unroll
    for (int j = 0; j < 2; ++j)
      pB[rg][j] = W + (size_t)(tnB + (wave * 3 + rg) * 16 + r_l) * K1 + j * 32 + kel;

  // LDS shorts: buffer p at p*20480 (40KB). A subtile (rg,j) at (rg*2+j)*512;
  // B at 8192 + (rg*2+j)*512.
#define STAGE_A(tt) do { const int p_ = (tt) & 1;                                \
    _Pragma("unroll")                                                            \
    for (int rg = 0; rg < 2; ++rg)                                               \
      _Pragma("unroll")                                                          \
      for (int j = 0; j < 2; ++j)                                                \
        gload_lds16(pA[rg][j] + (size_t)(tt) * 64,                               \
                    &lds[p_ * 20480 + ((wave * 2 + rg) * 2 + j) * 512]);         \
  } while (0)
#define STAGE_B(tt) do { const int p_ = (tt) & 1;                                \
    _Pragma("unroll")                                                            \
    for (int rg = 0; rg < 3; ++rg)                                               \
      _Pragma("unroll")                                                          \
      for (int j = 0; j < 2; ++j)                                                \
        gload_lds16(pB[rg][j] + (size_t)(tt) * 64,                               \
                    &lds[p_ * 20480 + 8192 + ((wave * 3 + rg) * 2 + j) * 512]);  \
  } while (0)

  const int loc = swz1k((lane & 15) * 64 + (lane >> 4) * 16);

  f32x4 acc[4][6];
#pragma unroll
  for (int m = 0; m < 4; ++m)
#pragma unroll
    for (int n = 0; n < 6; ++n) acc[m][n] = (f32x4){0.f, 0.f, 0.f, 0.f};

  STAGE_A(0); STAGE_B(0);   // 10 vmem ops

#define MFMA24(aV, bV) do {                                                      \
    _Pragma("unroll")                                                            \
    for (int n = 0; n < 6; ++n) {                                                \
      _Pragma("unroll")                                                          \
      for (int m = 0; m < 4; ++m)                                                \
        acc[m][n] = __builtin_amdgcn_mfma_f32_16x16x32_bf16(                     \
            aV[m], bV[n], acc[m][n], 0, 0, 0);                                   \
    } } while (0)

  const char* lchar = (const char*)lds;
  for (int t = 0; t < NT; ++t) {
    asm volatile("s_waitcnt vmcnt(0)" ::: "memory");
    __builtin_amdgcn_s_barrier();

    const char* base = lchar + (t & 1) * 40960;
    const char* bA = base + wm * 8192 + loc;            // 4 subtile-pairs
    const char* bB = base + 16384 + wn * 12288 + loc;   // 6 subtile-pairs

    bf16x8 a0[4], a1[4], b0[6], b1[6];
#pragma unroll
    for (int n = 0; n < 6; ++n) b0[n] = *(const bf16x8*)(bB + (2 * n + 0) * 1024);
#pragma unroll
    for (int m = 0; m < 4; ++m) a0[m] = *(const bf16x8*)(bA + (2 * m + 0) * 1024);
    if (t + 1 < NT) STAGE_A(t + 1);
#pragma unroll
    for (int n = 0; n < 6; ++n) b1[n] = *(const bf16x8*)(bB + (2 * n + 1) * 1024);
#pragma unroll
    for (int m = 0; m < 4; ++m) a1[m] = *(const bf16x8*)(bA + (2 * m + 1) * 1024);
    if (t + 1 < NT) STAGE_B(t + 1);

    __builtin_amdgcn_s_setprio(1);
    MFMA24(a0, b0);
    __builtin_amdgcn_s_setprio(0);
    __builtin_amdgcn_s_setprio(1);
    MFMA24(a1, b1);
    __builtin_amdgcn_s_setprio(0);
  }
#undef MFMA24
#undef STAGE_A
#undef STAGE_B

  // ---- epilogue: per-wave 3KB slab (16 rows x 192B, XOR bit5 by (row>>2)&1)
  // -> coalesced 16B stores. 16-col (and 8-col) groups never straddle a
  // 1024-col plane boundary, so activation/bias/dst are per-fn / per-chunk.
  unsigned short* slab = &lds[wave * 1536];
  const int l15 = lane & 15, lq4 = (lane >> 4) << 2;
  const int colg0 = tnB + wn * 96;
  const int rowg0 = tmB + wm * 64;
  const size_t BH = (size_t)B_DIM * H_DIM;

  float biasv[6];
  int amode[6];   // 0 sigmoid, 1 tanh, 2 relu
#pragma unroll
  for (int fn = 0; fn < 6; ++fn) {
    const int c = colg0 + fn * 16 + l15;
    if (c < 5120) {
      biasv[fn] = bWx[c] + bUx[c];
      amode[fn] = ((c >> 10) == 3) ? 1 : 0;
    } else {
      biasv[fn] = a1_b[c - 5120];
      amode[fn] = 2;
    }
  }
  __builtin_amdgcn_s_barrier();   // all K-loop LDS traffic fully retired
#pragma unroll
  for (int fm = 0; fm < 4; ++fm) {
#pragma unroll
    for (int fn = 0; fn < 6; ++fn) {
      f32x4 v = acc[fm][fn];
#pragma unroll
      for (int j = 0; j < 4; ++j) {
        const int row = lq4 + j;
        const float xv = v[j] + biasv[fn];
        const float res = (amode[fn] == 1) ? fast_tanh(xv)
                         : (amode[fn] == 0) ? fast_sigmoid(xv)
                         : fmaxf(xv, 0.f);
        const int byte = (row * 192 + (fn * 16 + l15) * 2) ^ (((row >> 2) & 1) << 5);
        slab[byte >> 1] = f2bf(res);
      }
    }
    asm volatile("s_waitcnt lgkmcnt(0)" ::: "memory");
    __builtin_amdgcn_sched_barrier(0);
#pragma unroll
    for (int p = 0; p < 3; ++p) {
      const int id = p * 64 + lane;
      const int row = id / 12, cc = id - row * 12;
      const int byte = (row * 192 + cc * 16) ^ (((row >> 2) & 1) << 5);
      bf16x8 pk = *(const bf16x8*)((const char*)slab + byte);
      const int col = colg0 + cc * 8;
      const size_t r = (size_t)(rowg0 + fm * 16 + row);
      unsigned short* dst;
      if (col < 5120) dst = gates + (size_t)(col >> 10) * BH + r * 1024 + (col & 1023);
      else            dst = a_hidden + r * 1024 + (col - 5120);
      *(bf16x8*)dst = pk;
    }
    asm volatile("s_waitcnt lgkmcnt(0)" ::: "memory");
    __builtin_amdgcn_sched_barrier(0);
  }
}

// ---------------------------------------------------------------------------
// gemm_body<NT, MODE>: R11's 128x128 structure (seg-1 + smalls), unchanged.
// MODE 1: N=2048: tn<8 A=A0 lda1024 -> fp32 out0; tn>=8 A=A1 lda2048 ->
//         relu bf16 out1
// MODE 2: N=1024 -> relu bf16 out1;  MODE 3: N=1024 -> fp32 out0
// ---------------------------------------------------------------------------
template <int NT, int MODE>
__device__ __forceinline__ void gemm_body(
    unsigned short* lds, const int bid,
    const unsigned short* __restrict__ A0,
    const unsigned short* __restrict__ A1,
    const unsigned short* __restrict__ W,
    const float* __restrict__ b0, const float* __restrict__ b1,
    void* __restrict__ out0, void* __restrict__ out1)
{
  constexpr int KDIM = NT * 64;
  constexpr int NTN  = (MODE == 1) ? 16 : 8;
  constexpr int NWG  = 32 * NTN;

  const int tid  = threadIdx.x;
  const int wave = tid >> 6;
  const int lane = tid & 63;
  const int wm = wave >> 1;
  const int wn = wave & 1;

  const int swz = (bid & 7) * (NWG / 8) + (bid >> 3);
  const int tm = swz / NTN, tn = swz % NTN;
  const int tmB = tm * 128, tnB = tn * 128;

  const unsigned short* Abase = A0;
  int lda = 1024;
  if (MODE == 1 && tn >= 8) { Abase = A1; lda = 2048; }

  const int sidx = swz1k(lane * 16);
  const int r_l  = sidx >> 6;
  const int kel  = (sidx & 63) >> 1;
  const unsigned short* pA[2][2];
  const unsigned short* pB[2][2];
#pragma unroll
  for (int rg = 0; rg < 2; ++rg)
#pragma unroll
    for (int j = 0; j < 2; ++j) {
      const int rr = wave * 32 + rg * 16 + r_l;
      const int kk0 = j * 32 + kel;
      pA[rg][j] = Abase + (size_t)(tmB + rr) * lda + kk0;
      pB[rg][j] = W + (size_t)(tnB + rr) * KDIM + kk0;
    }

#define STAGE_A(tt) do { const int p_ = (tt) & 1;                                \
    _Pragma("unroll")                                                            \
    for (int rg = 0; rg < 2; ++rg)                                               \
      _Pragma("unroll")                                                          \
      for (int j = 0; j < 2; ++j)                                                \
        gload_lds16(pA[rg][j] + (size_t)(tt) * 64,                               \
                    &lds[p_ * 16384 + ((wave * 2 + rg) * 2 + j) * 512]);         \
  } while (0)
#define STAGE_B(tt) do { const int p_ = (tt) & 1;                                \
    _Pragma("unroll")                                                            \
    for (int rg = 0; rg < 2; ++rg)                                               \
      _Pragma("unroll")                                                          \
      for (int j = 0; j < 2; ++j)                                                \
        gload_lds16(pB[rg][j] + (size_t)(tt) * 64,                               \
                    &lds[p_ * 16384 + 8192 + ((wave * 2 + rg) * 2 + j) * 512]);  \
  } while (0)

  const int loc = swz1k((lane & 15) * 64 + (lane >> 4) * 16);

  f32x4 acc[4][4];
#pragma unroll
  for (int m = 0; m < 4; ++m)
#pragma unroll
    for (int n = 0; n < 4; ++n) acc[m][n] = (f32x4){0.f, 0.f, 0.f, 0.f};

  STAGE_A(0); STAGE_B(0);

#define MFMA16(aV, bV) do {                                                      \
    _Pragma("unroll")                                                            \
    for (int n = 0; n < 4; ++n) {                                                \
      _Pragma("unroll")                                                          \
      for (int m = 0; m < 4; ++m)                                                \
        acc[m][n] = __builtin_amdgcn_mfma_f32_16x16x32_bf16(                     \
            aV[m], bV[n], acc[m][n], 0, 0, 0);                                   \
    } } while (0)

  const char* lchar = (const char*)lds;
  for (int t = 0; t < NT; ++t) {
    asm volatile("s_waitcnt vmcnt(0)" ::: "memory");
    __builtin_amdgcn_s_barrier();

    const char* base = lchar + (t & 1) * 32768;
    const char* bA = base + wm * 8192 + loc;
    const char* bB = base + 16384 + wn * 8192 + loc;

    bf16x8 a0[4], a1[4], b0v[4], b1v[4];
#pragma unroll
    for (int n = 0; n < 4; ++n) b0v[n] = *(const bf16x8*)(bB + (2 * n + 0) * 1024);
#pragma unroll
    for (int m = 0; m < 4; ++m) a0[m] = *(const bf16x8*)(bA + (2 * m + 0) * 1024);
    if (t + 1 < NT) STAGE_A(t + 1);
#pragma unroll
    for (int n = 0; n < 4; ++n) b1v[n] = *(const bf16x8*)(bB + (2 * n + 1) * 1024);
#pragma unroll
    for (int m = 0; m < 4; ++m) a1[m] = *(const bf16x8*)(bA + (2 * m + 1) * 1024);
    if (t + 1 < NT) STAGE_B(t + 1);

    __builtin_amdgcn_s_setprio(1);
    MFMA16(a0, b0v);
    __builtin_amdgcn_s_setprio(0);
    __builtin_amdgcn_s_setprio(1);
    MFMA16(a1, b1v);
    __builtin_amdgcn_s_setprio(0);
  }
#undef MFMA16
#undef STAGE_A
#undef STAGE_B

  const int l15 = lane & 15, lq4 = (lane >> 4) << 2;
  const int rowg0 = tmB + wm * 64;

  if ((MODE == 1 && tn < 8) || MODE == 3) {
    const int col0 = tn * 128 + wn * 64;
#pragma unroll
    for (int fn = 0; fn < 4; ++fn) {
      const int col = col0 + fn * 16 + l15;
      const float bias = b0[col];
#pragma unroll
      for (int fm = 0; fm < 4; ++fm) {
        f32x4 v = acc[fm][fn];
#pragma unroll
        for (int j = 0; j < 4; ++j) {
          const int r = rowg0 + fm * 16 + lq4 + j;
          ((float*)out0)[(size_t)r * 1024 + col] = v[j] + bias;
        }
      }
    }
    return;
  }

  unsigned short* slab = &lds[wave * 1024];
  const int lr8 = lane >> 3, lc8 = lane & 7;
  int colg0;
  unsigned short* outbase = (unsigned short*)out1;
  if (MODE == 1) colg0 = (tn - 8) * 128 + wn * 64;
  else           colg0 = tn * 128 + wn * 64;
  float biasv[4];
#pragma unroll
  for (int fn = 0; fn < 4; ++fn) biasv[fn] = b1[colg0 + fn * 16 + l15];
  __builtin_amdgcn_s_barrier();
#pragma unroll
  for (int fm = 0; fm < 4; ++fm) {
#pragma unroll
    for (int fn = 0; fn < 4; ++fn) {
      f32x4 v = acc[fm][fn];
#pragma unroll
      for (int j = 0; j < 4; ++j) {
        const int row = lq4 + j;
        const float res = fmaxf(v[j] + biasv[fn], 0.f);
        const int colb = ((fn * 16 + l15) * 2) ^ (((row >> 2) & 3) << 5);
        slab[(row * 128 + colb) >> 1] = f2bf(res);
      }
    }
    asm volatile("s_waitcnt lgkmcnt(0)" ::: "memory");
    __builtin_amdgcn_sched_barrier(0);
#pragma unroll
    for (int rd = 0; rd < 2; ++rd) {
      const int row = rd * 8 + lr8;
      const int cb = (lc8 * 16) ^ (((row >> 2) & 3) << 5);
      bf16x8 pk = *(const bf16x8*)((const char*)slab + row * 128 + cb);
      const size_t r = (size_t)(rowg0 + fm * 16 + row);
      *(bf16x8*)&outbase[r * 1024 + colg0 + lc8 * 8] = pk;
    }
    asm volatile("s_waitcnt lgkmcnt(0)" ::: "memory");
    __builtin_amdgcn_sched_barrier(0);
  }
}

// ---------------------------------------------------------------------------
// merged big GEMM: blocks [0,1024) = gates+a_hidden (128x192, 4x6 frags);
// [1024,1536) = ssg+r1 (128x128). 80 KB shared -> 2 blocks/CU. Grid 1536 =
// 3 full rounds of 512 co-resident blocks.
// ---------------------------------------------------------------------------
__global__ __launch_bounds__(256, 2) void gemm_big(
    const unsigned short* __restrict__ combined,
    const unsigned short* __restrict__ ssg_in,
    const unsigned short* __restrict__ W1,
    const unsigned short* __restrict__ W2,
    const float* __restrict__ bWx, const float* __restrict__ bUx,
    const float* __restrict__ a1_b,
    const float* __restrict__ ssg_b, const float* __restrict__ r1_b,
    unsigned short* __restrict__ gates,
    unsigned short* __restrict__ a_hidden,
    float* __restrict__ ssg_out,
    unsigned short* __restrict__ r1)
{
  __shared__ unsigned short lds[40960];  // 80 KiB
  const int bid = blockIdx.x;
  if (bid < 1024) {
    body192(lds, bid, combined, W1, bWx, bUx, a1_b, gates, a_hidden);
  } else {
    gemm_body<16, 1>(lds, bid - 1024, ssg_in, combined + 1024, W2,
                     ssg_b, r1_b, ssg_out, r1);
  }
}

// r2 / residual GEMMs on the 128x128 structure
template <int MODE>
__global__ __launch_bounds__(256, 2) void gemm_small(
    const unsigned short* __restrict__ A,
    const unsigned short* __restrict__ W,
    const float* __restrict__ bias,
    void* __restrict__ out)
{
  __shared__ unsigned short lds[32768];
  if (MODE == 2) gemm_body<16, 2>(lds, blockIdx.x, A, nullptr, W,
                                  nullptr, bias, nullptr, out);
  else           gemm_body<16, 3>(lds, blockIdx.x, A, nullptr, W,
                                  bias, nullptr, out, nullptr);
}

// ---------------------------------------------------------------------------
// final fused: per-row alpha (4-wave reduce) + vec4 elementwise cell update.
// ---------------------------------------------------------------------------
__global__ __launch_bounds__(256) void final_fused(
    const unsigned short* __restrict__ gates,
    const float* __restrict__ c_prev,
    const unsigned short* __restrict__ a_hidden,
    const float* __restrict__ a2_w, const float* __restrict__ a2_b,
    const float* __restrict__ residual,
    const float* __restrict__ ssg_new,
    float* __restrict__ h_out, float* __restrict__ c_out)
{
  __shared__ float red[5];
  const int r = blockIdx.x;
  const int tid = threadIdx.x;
  const size_t BH = (size_t)B_DIM * H_DIM;

  {
    ushort4 u = *(const ushort4*)&a_hidden[(size_t)r * 1024 + tid * 4];
    float4 w = *(const float4*)&a2_w[tid * 4];
    float s = bf2f(u.x) * w.x + bf2f(u.y) * w.y + bf2f(u.z) * w.z + bf2f(u.w) * w.w;
#pragma unroll
    for (int off = 32; off; off >>= 1) s += __shfl_xor(s, off);
    if ((tid & 63) == 0) red[tid >> 6] = s;
  }
  __syncthreads();
  if (tid == 0)
    red[4] = fast_sigmoid(red[0] + red[1] + red[2] + red[3] + a2_b[0]);
  __syncthreads();
  const float al = red[4];

  const size_t e = (size_t)r * 1024 + tid * 4;
  ushort4 iu = *(const ushort4*)&gates[e];
  ushort4 fu = *(const ushort4*)&gates[BH + e];
  ushort4 ou = *(const ushort4*)&gates[2 * BH + e];
  ushort4 cu = *(const ushort4*)&gates[3 * BH + e];
  ushort4 su = *(const ushort4*)&gates[4 * BH + e];
  float4 cp = *(const float4*)&c_prev[e];
  float4 rs = *(const float4*)&residual[e];
  float4 sg = *(const float4*)&ssg_new[e];
  float4 ho, co;
  co.x = bf2f(fu.x) * cp.x + bf2f(iu.x) * bf2f(cu.x) * bf2f(su.x) * al * sg.x + rs.x;
  co.y = bf2f(fu.y) * cp.y + bf2f(iu.y) * bf2f(cu.y) * bf2f(su.y) * al * sg.y + rs.y;
  co.z = bf2f(fu.z) * cp.z + bf2f(iu.z) * bf2f(cu.z) * bf2f(su.z) * al * sg.z + rs.z;
  co.w = bf2f(fu.w) * cp.w + bf2f(iu.w) * bf2f(cu.w) * bf2f(su.w) * al * sg.w + rs.w;
  ho.x = bf2f(ou.x) * fast_tanh(co.x);
  ho.y = bf2f(ou.y) * fast_tanh(co.y);
  ho.z = bf2f(ou.z) * fast_tanh(co.z);
  ho.w = bf2f(ou.w) * fast_tanh(co.w);
  *(float4*)&h_out[e] = ho;
  *(float4*)&c_out[e] = co;
}

// ---------------------------------------------------------------------------
extern "C" void kernel_launch(void* const* d_in, const int* in_sizes, int n_in,
                              void* d_out, int out_size, void* d_ws, size_t ws_size,
                              hipStream_t stream)
{
  (void)in_sizes; (void)n_in; (void)out_size; (void)ws_size;
  const float* x         = (const float*)d_in[0];
  const float* h_prev    = (const float*)d_in[1];
  const float* c_prev    = (const float*)d_in[2];
  const float* ssg_state = (const float*)d_in[3];
  const float* Wx        = (const float*)d_in[4];
  const float* bWx       = (const float*)d_in[5];
  const float* Ux        = (const float*)d_in[6];
  const float* bUx       = (const float*)d_in[7];
  const float* a1_w      = (const float*)d_in[8];
  const float* a1_b      = (const float*)d_in[9];
  const float* a2_w      = (const float*)d_in[10];
  const float* a2_b      = (const float*)d_in[11];
  const float* r1_w      = (const float*)d_in[12];
  const float* r1_b      = (const float*)d_in[13];
  const float* r2_w      = (const float*)d_in[14];
  const float* r2_b      = (const float*)d_in[15];
  const float* r3_w      = (const float*)d_in[16];
  const float* r3_b      = (const float*)d_in[17];
  const float* ssg_w     = (const float*)d_in[18];
  const float* ssg_b     = (const float*)d_in[19];

  char* ws = (char*)d_ws;
  unsigned short* combined = (unsigned short*)(ws);               // 16,777,216
  unsigned short* ssg_in   = (unsigned short*)(ws + 16777216);    //  8,388,608
  unsigned short* W1       = (unsigned short*)(ws + 33554432);    // 25,165,824
  unsigned short* W2       = (unsigned short*)(ws + 58720256);    //  4,194,304
  unsigned short* W3       = (unsigned short*)(ws + 62914560);    //  2,097,152
  unsigned short* W4       = (unsigned short*)(ws + 65011712);    //  2,097,152
  unsigned short* gates    = (unsigned short*)(ws + 67108864);    // 41,943,040
  unsigned short* a_hidden = (unsigned short*)(ws + 109051904);   //  8,388,608
  unsigned short* r1       = (unsigned short*)(ws + 117456896);   //  8,388,608
  unsigned short* r2       = (unsigned short*)(ws + 125845504);   //  8,388,608
  float*          residual = (float*)(ws + 134234112);            // 16,777,216

  float* h_out   = (float*)d_out;
  float* c_out   = h_out + (size_t)B_DIM * H_DIM;
  float* ssg_out = c_out + (size_t)B_DIM * H_DIM;

  prep_kernel<<<4096, 256, 0, stream>>>(x, h_prev, ssg_state, Wx, Ux, a1_w,
                                        ssg_w, r1_w, r2_w, r3_w,
                                        combined, ssg_in, W1, W2, W3, W4);

  gemm_big<<<1536, 256, 0, stream>>>(
      combined, ssg_in, W1, W2, bWx, bUx, a1_b, ssg_b, r1_b,
      gates, a_hidden, ssg_out, r1);

  gemm_small<2><<<256, 256, 0, stream>>>(r1, W3, r2_b, r2);

  gemm_small<3><<<256, 256, 0, stream>>>(r2, W4, r3_b, residual);

  final_fused<<<B_DIM, 256, 0, stream>>>(
      gates, c_prev, a_hidden, a2_w, a2_b, residual, ssg_out, h_out, c_out);
}

// Round 13
// 216.274 us; speedup vs baseline: 1.2476x; 1.0156x over previous
//
#include <hip/hip_runtime.h>
#include <hip/hip_bf16.h>

// Problem constants
#define B_DIM 4096
#define H_DIM 1024
#define K1    2048   // IN + H
#define N1    6144   // 5 gates * 1024 + a1 (1024)

typedef __attribute__((ext_vector_type(8))) short bf16x8;
typedef __attribute__((ext_vector_type(4))) float f32x4;

__device__ __forceinline__ unsigned short f2bf(float f) {
  unsigned int x = __float_as_uint(f);
  x += 0x7fffu + ((x >> 16) & 1u);   // RTNE
  return (unsigned short)(x >> 16);
}
__device__ __forceinline__ float bf2f(unsigned short u) {
  return __uint_as_float(((unsigned int)u) << 16);
}
__device__ __forceinline__ float fast_sigmoid(float x) {
  return __builtin_amdgcn_rcpf(1.0f + __expf(-x));
}
__device__ __forceinline__ float fast_tanh(float x) {
  return 1.0f - 2.0f * __builtin_amdgcn_rcpf(1.0f + __expf(2.0f * x));
}
__device__ __forceinline__ void gload_lds16(const void* g, void* l) {
  __builtin_amdgcn_global_load_lds(
      (const __attribute__((address_space(1))) void*)g,
      (__attribute__((address_space(3))) void*)l, 16, 0, 0);
}

// m201's st_16x32 swizzle: XOR byte-bit5 with bit9 within a 1024B subtile.
__device__ __forceinline__ int swz1k(int x) {
  return x ^ (((x >> 9) & 1) << 5);
}

// ---------------------------------------------------------------------------
// prep: build bf16 activations + weight panels in workspace (grid-stride vec4)
// ---------------------------------------------------------------------------
__global__ __launch_bounds__(256) void prep_kernel(
    const float* __restrict__ x, const float* __restrict__ h,
    const float* __restrict__ ssg_state,
    const float* __restrict__ Wx, const float* __restrict__ Ux,
    const float* __restrict__ a1_w,
    const float* __restrict__ ssg_w, const float* __restrict__ r1_w,
    const float* __restrict__ r2_w, const float* __restrict__ r3_w,
    unsigned short* __restrict__ combined,
    unsigned short* __restrict__ ssg_in,
    unsigned short* __restrict__ W1,
    unsigned short* __restrict__ W2,
    unsigned short* __restrict__ W3,
    unsigned short* __restrict__ W4)
{
  const size_t NV0 = (size_t)B_DIM * K1 / 4;      // combined
  const size_t NV1 = (size_t)B_DIM * H_DIM / 4;   // ssg_in
  const size_t NV3 = (size_t)N1 * K1 / 4;         // W1
  const size_t NV4 = (size_t)2048 * H_DIM / 4;    // W2
  const size_t NV5 = (size_t)H_DIM * H_DIM / 4;   // W3, W4
  const size_t total = NV0 + NV1 + NV3 + NV4 + NV5 + NV5;
  const size_t stride = (size_t)gridDim.x * blockDim.x;

  for (size_t v = (size_t)blockIdx.x * blockDim.x + threadIdx.x; v < total; v += stride) {
    size_t idx = v;
    const float* src;
    unsigned short* dst;
    if (idx < NV0) {
      size_t e = idx * 4, b = e >> 11, k = e & 2047;
      src = (k < 1024) ? &x[(b << 10) + k] : &h[(b << 10) + (k - 1024)];
      dst = &combined[e];
    } else if ((idx -= NV0) < NV1) {
      size_t e = idx * 4;
      float4 a = *(const float4*)&ssg_state[e];
      float4 c = *(const float4*)&h[e];
      ushort4 o;
      o.x = f2bf(a.x + c.x); o.y = f2bf(a.y + c.y);
      o.z = f2bf(a.z + c.z); o.w = f2bf(a.w + c.w);
      *(ushort4*)&ssg_in[e] = o;
      continue;
    } else if ((idx -= NV1) < NV3) {
      size_t e = idx * 4, n = e >> 11, k = e & 2047;
      if (n < 5120) src = (k < 1024) ? &Wx[(n << 10) + k] : &Ux[(n << 10) + (k - 1024)];
      else          src = &a1_w[((n - 5120) << 11) + k];
      dst = &W1[e];
    } else if ((idx -= NV3) < NV4) {
      size_t e = idx * 4, n = e >> 10, k = e & 1023;
      src = (n < 1024) ? &ssg_w[(n << 10) + k] : &r1_w[((n - 1024) << 10) + k];
      dst = &W2[e];
    } else if ((idx -= NV4) < NV5) {
      size_t e = idx * 4; src = &r2_w[e]; dst = &W3[e];
    } else {
      idx -= NV5;
      size_t e = idx * 4; src = &r3_w[e]; dst = &W4[e];
    }
    float4 a = *(const float4*)src;
    ushort4 o;
    o.x = f2bf(a.x); o.y = f2bf(a.y); o.z = f2bf(a.z); o.w = f2bf(a.w);
    *(ushort4*)dst = o;
  }
}

// ---------------------------------------------------------------------------
// body192: 128x192 tile, 4 waves 2x2 (per-wave 64x96, 4x6 frags), 1-barrier
// K-tile schedule, 80 KB LDS (2 blocks/CU). R12-verified, unchanged.
// ---------------------------------------------------------------------------
__device__ __forceinline__ void body192(
    unsigned short* lds, const int bid,
    const unsigned short* __restrict__ A,
    const unsigned short* __restrict__ W,
    const float* __restrict__ bWx, const float* __restrict__ bUx,
    const float* __restrict__ a1_b,
    unsigned short* __restrict__ gates,
    unsigned short* __restrict__ a_hidden)
{
  constexpr int NT  = 32;       // K = 2048
  constexpr int NTN = 32;       // 6144 / 192
  constexpr int NWG = 32 * NTN; // 1024

  const int tid  = threadIdx.x;
  const int wave = tid >> 6;
  const int lane = tid & 63;
  const int wm = wave >> 1;     // row half (64)
  const int wn = wave & 1;      // col half (96)

  const int swz = (bid & 7) * (NWG / 8) + (bid >> 3);
  const int tm = swz / NTN, tn = swz % NTN;
  const int tmB = tm * 128, tnB = tn * 192;

  const int sidx = swz1k(lane * 16);
  const int r_l  = sidx >> 6;
  const int kel  = (sidx & 63) >> 1;
  const unsigned short* pA[2][2];
  const unsigned short* pB[3][2];
#pragma unroll
  for (int rg = 0; rg < 2; ++rg)
#pragma unroll
    for (int j = 0; j < 2; ++j)
      pA[rg][j] = A + (size_t)(tmB + (wave * 2 + rg) * 16 + r_l) * K1 + j * 32 + kel;
#pragma unroll
  for (int rg = 0; rg < 3; ++rg)
#pragma unroll
    for (int j = 0; j < 2; ++j)
      pB[rg][j] = W + (size_t)(tnB + (wave * 3 + rg) * 16 + r_l) * K1 + j * 32 + kel;

#define STAGE_A(tt) do { const int p_ = (tt) & 1;                                \
    _Pragma("unroll")                                                            \
    for (int rg = 0; rg < 2; ++rg)                                               \
      _Pragma("unroll")                                                          \
      for (int j = 0; j < 2; ++j)                                                \
        gload_lds16(pA[rg][j] + (size_t)(tt) * 64,                               \
                    &lds[p_ * 20480 + ((wave * 2 + rg) * 2 + j) * 512]);         \
  } while (0)
#define STAGE_B(tt) do { const int p_ = (tt) & 1;                                \
    _Pragma("unroll")                                                            \
    for (int rg = 0; rg < 3; ++rg)                                               \
      _Pragma("unroll")                                                          \
      for (int j = 0; j < 2; ++j)                                                \
        gload_lds16(pB[rg][j] + (size_t)(tt) * 64,                               \
                    &lds[p_ * 20480 + 8192 + ((wave * 3 + rg) * 2 + j) * 512]);  \
  } while (0)

  const int loc = swz1k((lane & 15) * 64 + (lane >> 4) * 16);

  f32x4 acc[4][6];
#pragma unroll
  for (int m = 0; m < 4; ++m)
#pragma unroll
    for (int n = 0; n < 6; ++n) acc[m][n] = (f32x4){0.f, 0.f, 0.f, 0.f};

  STAGE_A(0); STAGE_B(0);   // 10 vmem ops

#define MFMA24(aV, bV) do {                                                      \
    _Pragma("unroll")                                                            \
    for (int n = 0; n < 6; ++n) {                                                \
      _Pragma("unroll")                                                          \
      for (int m = 0; m < 4; ++m)                                                \
        acc[m][n] = __builtin_amdgcn_mfma_f32_16x16x32_bf16(                     \
            aV[m], bV[n], acc[m][n], 0, 0, 0);                                   \
    } } while (0)

  const char* lchar = (const char*)lds;
  for (int t = 0; t < NT; ++t) {
    asm volatile("s_waitcnt vmcnt(0)" ::: "memory");
    __builtin_amdgcn_s_barrier();

    const char* base = lchar + (t & 1) * 40960;
    const char* bA = base + wm * 8192 + loc;
    const char* bB = base + 16384 + wn * 12288 + loc;

    bf16x8 a0[4], a1[4], b0[6], b1[6];
#pragma unroll
    for (int n = 0; n < 6; ++n) b0[n] = *(const bf16x8*)(bB + (2 * n + 0) * 1024);
#pragma unroll
    for (int m = 0; m < 4; ++m) a0[m] = *(const bf16x8*)(bA + (2 * m + 0) * 1024);
    if (t + 1 < NT) STAGE_A(t + 1);
#pragma unroll
    for (int n = 0; n < 6; ++n) b1[n] = *(const bf16x8*)(bB + (2 * n + 1) * 1024);
#pragma unroll
    for (int m = 0; m < 4; ++m) a1[m] = *(const bf16x8*)(bA + (2 * m + 1) * 1024);
    if (t + 1 < NT) STAGE_B(t + 1);

    __builtin_amdgcn_s_setprio(1);
    MFMA24(a0, b0);
    __builtin_amdgcn_s_setprio(0);
    __builtin_amdgcn_s_setprio(1);
    MFMA24(a1, b1);
    __builtin_amdgcn_s_setprio(0);
  }
#undef MFMA24
#undef STAGE_A
#undef STAGE_B

  unsigned short* slab = &lds[wave * 1536];
  const int l15 = lane & 15, lq4 = (lane >> 4) << 2;
  const int colg0 = tnB + wn * 96;
  const int rowg0 = tmB + wm * 64;
  const size_t BH = (size_t)B_DIM * H_DIM;

  float biasv[6];
  int amode[6];   // 0 sigmoid, 1 tanh, 2 relu
#pragma unroll
  for (int fn = 0; fn < 6; ++fn) {
    const int c = colg0 + fn * 16 + l15;
    if (c < 5120) {
      biasv[fn] = bWx[c] + bUx[c];
      amode[fn] = ((c >> 10) == 3) ? 1 : 0;
    } else {
      biasv[fn] = a1_b[c - 5120];
      amode[fn] = 2;
    }
  }
  __builtin_amdgcn_s_barrier();
#pragma unroll
  for (int fm = 0; fm < 4; ++fm) {
#pragma unroll
    for (int fn = 0; fn < 6; ++fn) {
      f32x4 v = acc[fm][fn];
#pragma unroll
      for (int j = 0; j < 4; ++j) {
        const int row = lq4 + j;
        const float xv = v[j] + biasv[fn];
        const float res = (amode[fn] == 1) ? fast_tanh(xv)
                         : (amode[fn] == 0) ? fast_sigmoid(xv)
                         : fmaxf(xv, 0.f);
        const int byte = (row * 192 + (fn * 16 + l15) * 2) ^ (((row >> 2) & 1) << 5);
        slab[byte >> 1] = f2bf(res);
      }
    }
    asm volatile("s_waitcnt lgkmcnt(0)" ::: "memory");
    __builtin_amdgcn_sched_barrier(0);
#pragma unroll
    for (int p = 0; p < 3; ++p) {
      const int id = p * 64 + lane;
      const int row = id / 12, cc = id - row * 12;
      const int byte = (row * 192 + cc * 16) ^ (((row >> 2) & 1) << 5);
      bf16x8 pk = *(const bf16x8*)((const char*)slab + byte);
      const int col = colg0 + cc * 8;
      const size_t r = (size_t)(rowg0 + fm * 16 + row);
      unsigned short* dst;
      if (col < 5120) dst = gates + (size_t)(col >> 10) * BH + r * 1024 + (col & 1023);
      else            dst = a_hidden + r * 1024 + (col - 5120);
      *(bf16x8*)dst = pk;
    }
    asm volatile("s_waitcnt lgkmcnt(0)" ::: "memory");
    __builtin_amdgcn_sched_barrier(0);
  }
}

// ---------------------------------------------------------------------------
// gemm_body<NT, MODE=1>: R11's 128x128 structure for ssg+r1, unchanged.
// ---------------------------------------------------------------------------
template <int NT, int MODE>
__device__ __forceinline__ void gemm_body(
    unsigned short* lds, const int bid,
    const unsigned short* __restrict__ A0,
    const unsigned short* __restrict__ A1,
    const unsigned short* __restrict__ W,
    const float* __restrict__ b0, const float* __restrict__ b1,
    void* __restrict__ out0, void* __restrict__ out1)
{
  constexpr int KDIM = NT * 64;
  constexpr int NTN  = 16;
  constexpr int NWG  = 32 * NTN;

  const int tid  = threadIdx.x;
  const int wave = tid >> 6;
  const int lane = tid & 63;
  const int wm = wave >> 1;
  const int wn = wave & 1;

  const int swz = (bid & 7) * (NWG / 8) + (bid >> 3);
  const int tm = swz / NTN, tn = swz % NTN;
  const int tmB = tm * 128, tnB = tn * 128;

  const unsigned short* Abase = A0;
  int lda = 1024;
  if (tn >= 8) { Abase = A1; lda = 2048; }

  const int sidx = swz1k(lane * 16);
  const int r_l  = sidx >> 6;
  const int kel  = (sidx & 63) >> 1;
  const unsigned short* pA[2][2];
  const unsigned short* pB[2][2];
#pragma unroll
  for (int rg = 0; rg < 2; ++rg)
#pragma unroll
    for (int j = 0; j < 2; ++j) {
      const int rr = wave * 32 + rg * 16 + r_l;
      const int kk0 = j * 32 + kel;
      pA[rg][j] = Abase + (size_t)(tmB + rr) * lda + kk0;
      pB[rg][j] = W + (size_t)(tnB + rr) * KDIM + kk0;
    }

#define STAGE_A(tt) do { const int p_ = (tt) & 1;                                \
    _Pragma("unroll")                                                            \
    for (int rg = 0; rg < 2; ++rg)                                               \
      _Pragma("unroll")                                                          \
      for (int j = 0; j < 2; ++j)                                                \
        gload_lds16(pA[rg][j] + (size_t)(tt) * 64,                               \
                    &lds[p_ * 16384 + ((wave * 2 + rg) * 2 + j) * 512]);         \
  } while (0)
#define STAGE_B(tt) do { const int p_ = (tt) & 1;                                \
    _Pragma("unroll")                                                            \
    for (int rg = 0; rg < 2; ++rg)                                               \
      _Pragma("unroll")                                                          \
      for (int j = 0; j < 2; ++j)                                                \
        gload_lds16(pB[rg][j] + (size_t)(tt) * 64,                               \
                    &lds[p_ * 16384 + 8192 + ((wave * 2 + rg) * 2 + j) * 512]);  \
  } while (0)

  const int loc = swz1k((lane & 15) * 64 + (lane >> 4) * 16);

  f32x4 acc[4][4];
#pragma unroll
  for (int m = 0; m < 4; ++m)
#pragma unroll
    for (int n = 0; n < 4; ++n) acc[m][n] = (f32x4){0.f, 0.f, 0.f, 0.f};

  STAGE_A(0); STAGE_B(0);

#define MFMA16(aV, bV) do {                                                      \
    _Pragma("unroll")                                                            \
    for (int n = 0; n < 4; ++n) {                                                \
      _Pragma("unroll")                                                          \
      for (int m = 0; m < 4; ++m)                                                \
        acc[m][n] = __builtin_amdgcn_mfma_f32_16x16x32_bf16(                     \
            aV[m], bV[n], acc[m][n], 0, 0, 0);                                   \
    } } while (0)

  const char* lchar = (const char*)lds;
  for (int t = 0; t < NT; ++t) {
    asm volatile("s_waitcnt vmcnt(0)" ::: "memory");
    __builtin_amdgcn_s_barrier();

    const char* base = lchar + (t & 1) * 32768;
    const char* bA = base + wm * 8192 + loc;
    const char* bB = base + 16384 + wn * 8192 + loc;

    bf16x8 a0[4], a1[4], b0v[4], b1v[4];
#pragma unroll
    for (int n = 0; n < 4; ++n) b0v[n] = *(const bf16x8*)(bB + (2 * n + 0) * 1024);
#pragma unroll
    for (int m = 0; m < 4; ++m) a0[m] = *(const bf16x8*)(bA + (2 * m + 0) * 1024);
    if (t + 1 < NT) STAGE_A(t + 1);
#pragma unroll
    for (int n = 0; n < 4; ++n) b1v[n] = *(const bf16x8*)(bB + (2 * n + 1) * 1024);
#pragma unroll
    for (int m = 0; m < 4; ++m) a1[m] = *(const bf16x8*)(bA + (2 * m + 1) * 1024);
    if (t + 1 < NT) STAGE_B(t + 1);

    __builtin_amdgcn_s_setprio(1);
    MFMA16(a0, b0v);
    __builtin_amdgcn_s_setprio(0);
    __builtin_amdgcn_s_setprio(1);
    MFMA16(a1, b1v);
    __builtin_amdgcn_s_setprio(0);
  }
#undef MFMA16
#undef STAGE_A
#undef STAGE_B

  const int l15 = lane & 15, lq4 = (lane >> 4) << 2;
  const int rowg0 = tmB + wm * 64;

  if (tn < 8) {
    const int col0 = tn * 128 + wn * 64;
#pragma unroll
    for (int fn = 0; fn < 4; ++fn) {
      const int col = col0 + fn * 16 + l15;
      const float bias = b0[col];
#pragma unroll
      for (int fm = 0; fm < 4; ++fm) {
        f32x4 v = acc[fm][fn];
#pragma unroll
        for (int j = 0; j < 4; ++j) {
          const int r = rowg0 + fm * 16 + lq4 + j;
          ((float*)out0)[(size_t)r * 1024 + col] = v[j] + bias;
        }
      }
    }
    return;
  }

  unsigned short* slab = &lds[wave * 1024];
  const int lr8 = lane >> 3, lc8 = lane & 7;
  const int colg0 = (tn - 8) * 128 + wn * 64;
  unsigned short* outbase = (unsigned short*)out1;
  float biasv[4];
#pragma unroll
  for (int fn = 0; fn < 4; ++fn) biasv[fn] = b1[colg0 + fn * 16 + l15];
  __builtin_amdgcn_s_barrier();
#pragma unroll
  for (int fm = 0; fm < 4; ++fm) {
#pragma unroll
    for (int fn = 0; fn < 4; ++fn) {
      f32x4 v = acc[fm][fn];
#pragma unroll
      for (int j = 0; j < 4; ++j) {
        const int row = lq4 + j;
        const float res = fmaxf(v[j] + biasv[fn], 0.f);
        const int colb = ((fn * 16 + l15) * 2) ^ (((row >> 2) & 3) << 5);
        slab[(row * 128 + colb) >> 1] = f2bf(res);
      }
    }
    asm volatile("s_waitcnt lgkmcnt(0)" ::: "memory");
    __builtin_amdgcn_sched_barrier(0);
#pragma unroll
    for (int rd = 0; rd < 2; ++rd) {
      const int row = rd * 8 + lr8;
      const int cb = (lc8 * 16) ^ (((row >> 2) & 3) << 5);
      bf16x8 pk = *(const bf16x8*)((const char*)slab + row * 128 + cb);
      const size_t r = (size_t)(rowg0 + fm * 16 + row);
      *(bf16x8*)&outbase[r * 1024 + colg0 + lc8 * 8] = pk;
    }
    asm volatile("s_waitcnt lgkmcnt(0)" ::: "memory");
    __builtin_amdgcn_sched_barrier(0);
  }
}

// ---------------------------------------------------------------------------
// merged big GEMM: blocks [0,1024) = gates+a_hidden (128x192); [1024,1536) =
// ssg+r1 (128x128). 80 KB shared -> 2 blocks/CU.
// ---------------------------------------------------------------------------
__global__ __launch_bounds__(256, 2) void gemm_big(
    const unsigned short* __restrict__ combined,
    const unsigned short* __restrict__ ssg_in,
    const unsigned short* __restrict__ W1,
    const unsigned short* __restrict__ W2,
    const float* __restrict__ bWx, const float* __restrict__ bUx,
    const float* __restrict__ a1_b,
    const float* __restrict__ ssg_b, const float* __restrict__ r1_b,
    unsigned short* __restrict__ gates,
    unsigned short* __restrict__ a_hidden,
    float* __restrict__ ssg_out,
    unsigned short* __restrict__ r1)
{
  __shared__ unsigned short lds[40960];  // 80 KiB
  const int bid = blockIdx.x;
  if (bid < 1024) {
    body192(lds, bid, combined, W1, bWx, bUx, a1_b, gates, a_hidden);
  } else {
    gemm_body<16, 1>(lds, bid - 1024, ssg_in, combined + 1024, W2,
                     ssg_b, r1_b, ssg_out, r1);
  }
}

// ---------------------------------------------------------------------------
// gemm_small64<MODE>: 64x128 tile, 4 waves 2x2 (per-wave 32x64, 2x4 frags),
// same 1-barrier schedule, 48 KB LDS -> 3 blocks/CU. Grid = 64*8 = 512
// blocks, ALL co-resident (R12's 256-block version left half the CUs idle).
// MODE 2: relu -> bf16 out.  MODE 3: fp32 + bias out.
// ---------------------------------------------------------------------------
template <int MODE>
__global__ __launch_bounds__(256, 3) void gemm_small64(
    const unsigned short* __restrict__ A,
    const unsigned short* __restrict__ W,
    const float* __restrict__ bias,
    void* __restrict__ out)
{
  __shared__ unsigned short lds[24576];  // 48 KiB: 2 buffers x 12288 shorts
  constexpr int NT = 16;                 // K = 1024

  const int tid  = threadIdx.x;
  const int wave = tid >> 6;
  const int lane = tid & 63;
  const int wm = wave >> 1;   // row half (32)
  const int wn = wave & 1;    // col half (64)

  const int bid = blockIdx.x;
  const int swz = (bid & 7) * 64 + (bid >> 3);   // NWG = 512, bijective
  const int tm = swz >> 3, tn = swz & 7;
  const int tmB = tm * 64, tnB = tn * 128;

  const int sidx = swz1k(lane * 16);
  const int r_l  = sidx >> 6;
  const int kel  = (sidx & 63) >> 1;
  // A: 4 row-subtiles, wave stages subtile 'wave'; B: 8, wave stages 2.
  const unsigned short* pA[2];
  const unsigned short* pB[2][2];
#pragma unroll
  for (int j = 0; j < 2; ++j)
    pA[j] = A + (size_t)(tmB + wave * 16 + r_l) * 1024 + j * 32 + kel;
#pragma unroll
  for (int rg = 0; rg < 2; ++rg)
#pragma unroll
    for (int j = 0; j < 2; ++j)
      pB[rg][j] = W + (size_t)(tnB + (wave * 2 + rg) * 16 + r_l) * 1024 + j * 32 + kel;

  // LDS shorts: buffer p at p*12288; A region 4096 shorts (8KB), B at +4096.
#define STAGE_A(tt) do { const int p_ = (tt) & 1;                                \
    _Pragma("unroll")                                                            \
    for (int j = 0; j < 2; ++j)                                                  \
      gload_lds16(pA[j] + (size_t)(tt) * 64,                                     \
                  &lds[p_ * 12288 + (wave * 2 + j) * 512]);                      \
  } while (0)
#define STAGE_B(tt) do { const int p_ = (tt) & 1;                                \
    _Pragma("unroll")                                                            \
    for (int rg = 0; rg < 2; ++rg)                                               \
      _Pragma("unroll")                                                          \
      for (int j = 0; j < 2; ++j)                                                \
        gload_lds16(pB[rg][j] + (size_t)(tt) * 64,                               \
                    &lds[p_ * 12288 + 4096 + ((wave * 2 + rg) * 2 + j) * 512]);  \
  } while (0)

  const int loc = swz1k((lane & 15) * 64 + (lane >> 4) * 16);

  f32x4 acc[2][4];
#pragma unroll
  for (int m = 0; m < 2; ++m)
#pragma unroll
    for (int n = 0; n < 4; ++n) acc[m][n] = (f32x4){0.f, 0.f, 0.f, 0.f};

  STAGE_A(0); STAGE_B(0);   // 6 vmem ops

  const char* lchar = (const char*)lds;
  for (int t = 0; t < NT; ++t) {
    asm volatile("s_waitcnt vmcnt(0)" ::: "memory");
    __builtin_amdgcn_s_barrier();

    const char* base = lchar + (t & 1) * 24576;
    const char* bA = base + wm * 4096 + loc;          // 2 subtile-pairs
    const char* bB = base + 8192 + wn * 8192 + loc;   // 4 subtile-pairs

    bf16x8 a0[2], a1[2], b0[4], b1[4];
#pragma unroll
    for (int n = 0; n < 4; ++n) b0[n] = *(const bf16x8*)(bB + (2 * n + 0) * 1024);
#pragma unroll
    for (int m = 0; m < 2; ++m) a0[m] = *(const bf16x8*)(bA + (2 * m + 0) * 1024);
    if (t + 1 < NT) STAGE_A(t + 1);
#pragma unroll
    for (int n = 0; n < 4; ++n) b1[n] = *(const bf16x8*)(bB + (2 * n + 1) * 1024);
#pragma unroll
    for (int m = 0; m < 2; ++m) a1[m] = *(const bf16x8*)(bA + (2 * m + 1) * 1024);
    if (t + 1 < NT) STAGE_B(t + 1);

    __builtin_amdgcn_s_setprio(1);
#pragma unroll
    for (int n = 0; n < 4; ++n)
#pragma unroll
      for (int m = 0; m < 2; ++m)
        acc[m][n] = __builtin_amdgcn_mfma_f32_16x16x32_bf16(a0[m], b0[n], acc[m][n], 0, 0, 0);
    __builtin_amdgcn_s_setprio(0);
    __builtin_amdgcn_s_setprio(1);
#pragma unroll
    for (int n = 0; n < 4; ++n)
#pragma unroll
      for (int m = 0; m < 2; ++m)
        acc[m][n] = __builtin_amdgcn_mfma_f32_16x16x32_bf16(a1[m], b1[n], acc[m][n], 0, 0, 0);
    __builtin_amdgcn_s_setprio(0);
  }
#undef STAGE_A
#undef STAGE_B

  const int l15 = lane & 15, lq4 = (lane >> 4) << 2;
  const int rowg0 = tmB + wm * 32;

  if (MODE == 3) {
    const int col0 = tnB + wn * 64;
#pragma unroll
    for (int fn = 0; fn < 4; ++fn) {
      const int col = col0 + fn * 16 + l15;
      const float bv = bias[col];
#pragma unroll
      for (int fm = 0; fm < 2; ++fm) {
        f32x4 v = acc[fm][fn];
#pragma unroll
        for (int j = 0; j < 4; ++j) {
          const int r = rowg0 + fm * 16 + lq4 + j;
          ((float*)out)[(size_t)r * 1024 + col] = v[j] + bv;
        }
      }
    }
    return;
  }

  // MODE 2: relu -> bf16 via per-wave slab restage
  unsigned short* slab = &lds[wave * 1024];
  const int lr8 = lane >> 3, lc8 = lane & 7;
  const int colg0 = tnB + wn * 64;
  unsigned short* outbase = (unsigned short*)out;
  float biasv[4];
#pragma unroll
  for (int fn = 0; fn < 4; ++fn) biasv[fn] = bias[colg0 + fn * 16 + l15];
  __builtin_amdgcn_s_barrier();
#pragma unroll
  for (int fm = 0; fm < 2; ++fm) {
#pragma unroll
    for (int fn = 0; fn < 4; ++fn) {
      f32x4 v = acc[fm][fn];
#pragma unroll
      for (int j = 0; j < 4; ++j) {
        const int row = lq4 + j;
        const float res = fmaxf(v[j] + biasv[fn], 0.f);
        const int colb = ((fn * 16 + l15) * 2) ^ (((row >> 2) & 3) << 5);
        slab[(row * 128 + colb) >> 1] = f2bf(res);
      }
    }
    asm volatile("s_waitcnt lgkmcnt(0)" ::: "memory");
    __builtin_amdgcn_sched_barrier(0);
#pragma unroll
    for (int rd = 0; rd < 2; ++rd) {
      const int row = rd * 8 + lr8;
      const int cb = (lc8 * 16) ^ (((row >> 2) & 3) << 5);
      bf16x8 pk = *(const bf16x8*)((const char*)slab + row * 128 + cb);
      const size_t r = (size_t)(rowg0 + fm * 16 + row);
      *(bf16x8*)&outbase[r * 1024 + colg0 + lc8 * 8] = pk;
    }
    asm volatile("s_waitcnt lgkmcnt(0)" ::: "memory");
    __builtin_amdgcn_sched_barrier(0);
  }
}

// ---------------------------------------------------------------------------
// final fused: per-row alpha (4-wave reduce) + vec4 elementwise cell update.
// ---------------------------------------------------------------------------
__global__ __launch_bounds__(256) void final_fused(
    const unsigned short* __restrict__ gates,
    const float* __restrict__ c_prev,
    const unsigned short* __restrict__ a_hidden,
    const float* __restrict__ a2_w, const float* __restrict__ a2_b,
    const float* __restrict__ residual,
    const float* __restrict__ ssg_new,
    float* __restrict__ h_out, float* __restrict__ c_out)
{
  __shared__ float red[5];
  const int r = blockIdx.x;
  const int tid = threadIdx.x;
  const size_t BH = (size_t)B_DIM * H_DIM;

  {
    ushort4 u = *(const ushort4*)&a_hidden[(size_t)r * 1024 + tid * 4];
    float4 w = *(const float4*)&a2_w[tid * 4];
    float s = bf2f(u.x) * w.x + bf2f(u.y) * w.y + bf2f(u.z) * w.z + bf2f(u.w) * w.w;
#pragma unroll
    for (int off = 32; off; off >>= 1) s += __shfl_xor(s, off);
    if ((tid & 63) == 0) red[tid >> 6] = s;
  }
  __syncthreads();
  if (tid == 0)
    red[4] = fast_sigmoid(red[0] + red[1] + red[2] + red[3] + a2_b[0]);
  __syncthreads();
  const float al = red[4];

  const size_t e = (size_t)r * 1024 + tid * 4;
  ushort4 iu = *(const ushort4*)&gates[e];
  ushort4 fu = *(const ushort4*)&gates[BH + e];
  ushort4 ou = *(const ushort4*)&gates[2 * BH + e];
  ushort4 cu = *(const ushort4*)&gates[3 * BH + e];
  ushort4 su = *(const ushort4*)&gates[4 * BH + e];
  float4 cp = *(const float4*)&c_prev[e];
  float4 rs = *(const float4*)&residual[e];
  float4 sg = *(const float4*)&ssg_new[e];
  float4 ho, co;
  co.x = bf2f(fu.x) * cp.x + bf2f(iu.x) * bf2f(cu.x) * bf2f(su.x) * al * sg.x + rs.x;
  co.y = bf2f(fu.y) * cp.y + bf2f(iu.y) * bf2f(cu.y) * bf2f(su.y) * al * sg.y + rs.y;
  co.z = bf2f(fu.z) * cp.z + bf2f(iu.z) * bf2f(cu.z) * bf2f(su.z) * al * sg.z + rs.z;
  co.w = bf2f(fu.w) * cp.w + bf2f(iu.w) * bf2f(cu.w) * bf2f(su.w) * al * sg.w + rs.w;
  ho.x = bf2f(ou.x) * fast_tanh(co.x);
  ho.y = bf2f(ou.y) * fast_tanh(co.y);
  ho.z = bf2f(ou.z) * fast_tanh(co.z);
  ho.w = bf2f(ou.w) * fast_tanh(co.w);
  *(float4*)&h_out[e] = ho;
  *(float4*)&c_out[e] = co;
}

// ---------------------------------------------------------------------------
extern "C" void kernel_launch(void* const* d_in, const int* in_sizes, int n_in,
                              void* d_out, int out_size, void* d_ws, size_t ws_size,
                              hipStream_t stream)
{
  (void)in_sizes; (void)n_in; (void)out_size; (void)ws_size;
  const float* x         = (const float*)d_in[0];
  const float* h_prev    = (const float*)d_in[1];
  const float* c_prev    = (const float*)d_in[2];
  const float* ssg_state = (const float*)d_in[3];
  const float* Wx        = (const float*)d_in[4];
  const float* bWx       = (const float*)d_in[5];
  const float* Ux        = (const float*)d_in[6];
  const float* bUx       = (const float*)d_in[7];
  const float* a1_w      = (const float*)d_in[8];
  const float* a1_b      = (const float*)d_in[9];
  const float* a2_w      = (const float*)d_in[10];
  const float* a2_b      = (const float*)d_in[11];
  const float* r1_w      = (const float*)d_in[12];
  const float* r1_b      = (const float*)d_in[13];
  const float* r2_w      = (const float*)d_in[14];
  const float* r2_b      = (const float*)d_in[15];
  const float* r3_w      = (const float*)d_in[16];
  const float* r3_b      = (const float*)d_in[17];
  const float* ssg_w     = (const float*)d_in[18];
  const float* ssg_b     = (const float*)d_in[19];

  char* ws = (char*)d_ws;
  unsigned short* combined = (unsigned short*)(ws);               // 16,777,216
  unsigned short* ssg_in   = (unsigned short*)(ws + 16777216);    //  8,388,608
  unsigned short* W1       = (unsigned short*)(ws + 33554432);    // 25,165,824
  unsigned short* W2       = (unsigned short*)(ws + 58720256);    //  4,194,304
  unsigned short* W3       = (unsigned short*)(ws + 62914560);    //  2,097,152
  unsigned short* W4       = (unsigned short*)(ws + 65011712);    //  2,097,152
  unsigned short* gates    = (unsigned short*)(ws + 67108864);    // 41,943,040
  unsigned short* a_hidden = (unsigned short*)(ws + 109051904);   //  8,388,608
  unsigned short* r1       = (unsigned short*)(ws + 117456896);   //  8,388,608
  unsigned short* r2       = (unsigned short*)(ws + 125845504);   //  8,388,608
  float*          residual = (float*)(ws + 134234112);            // 16,777,216

  float* h_out   = (float*)d_out;
  float* c_out   = h_out + (size_t)B_DIM * H_DIM;
  float* ssg_out = c_out + (size_t)B_DIM * H_DIM;

  prep_kernel<<<4096, 256, 0, stream>>>(x, h_prev, ssg_state, Wx, Ux, a1_w,
                                        ssg_w, r1_w, r2_w, r3_w,
                                        combined, ssg_in, W1, W2, W3, W4);

  gemm_big<<<1536, 256, 0, stream>>>(
      combined, ssg_in, W1, W2, bWx, bUx, a1_b, ssg_b, r1_b,
      gates, a_hidden, ssg_out, r1);

  gemm_small64<2><<<512, 256, 0, stream>>>(r1, W3, r2_b, r2);

  gemm_small64<3><<<512, 256, 0, stream>>>(r2, W4, r3_b, residual);

  final_fused<<<B_DIM, 256, 0, stream>>>(
      gates, c_prev, a_hidden, a2_w, a2_b, residual, ssg_out, h_out, c_out);
}